// Round 1
// baseline (24404.121 us; speedup 1.0000x reference)
//
#include <hip/hip_runtime.h>

typedef unsigned short u16;
typedef __bf16 bf16x8 __attribute__((ext_vector_type(8)));
typedef float f32x4 __attribute__((ext_vector_type(4)));
typedef u16 u16x8 __attribute__((ext_vector_type(8)));
typedef u16 u16x4 __attribute__((ext_vector_type(4)));

__device__ __forceinline__ u16 f2bf(float f){
  unsigned u = __float_as_uint(f);
  u += 0x7FFFu + ((u >> 16) & 1u);   // RNE
  return (u16)(u >> 16);
}

// ---------------- weight f32 -> bf16 (4 elems/thread) ----------------
__global__ __launch_bounds__(256) void conv_bf16(const float* __restrict__ src, u16* __restrict__ dst){
  size_t i = ((size_t)blockIdx.x * 256 + threadIdx.x) * 4;
  f32x4 v = *(const f32x4*)(src + i);
  u16x4 o;
#pragma unroll
  for (int j = 0; j < 4; ++j) o[j] = f2bf(v[j]);
  *(u16x4*)(dst + i) = o;
}

// ---------------- embedding + positional encoding ----------------
__global__ __launch_bounds__(256) void embed_k(const int* __restrict__ data, const float* __restrict__ emb,
                                               float* __restrict__ h, u16* __restrict__ hbf){
  int idx = blockIdx.x * 256 + threadIdx.x;       // 0 .. 2M-1
  int r = idx >> 10, d = idx & 1023;              // r = i*4+b
  int i = r >> 2;
  int e = data[r];
  float val = emb[(size_t)e * 1024 + d] * 32.0f;  // sqrt(1024)
  float pos = (float)(511 - i);
  int t = d & 511;
  float freq = powf(10000.0f, -(float)t * (1.0f / 512.0f));
  float ang = pos * freq;
  val += (d < 512) ? sinf(ang) : cosf(ang);
  h[idx] = val;
  hbf[idx] = f2bf(val);
}

// ---------------- build concat(mems[l], h) in bf16 ----------------
__global__ __launch_bounds__(256) void build_c_k(const float* __restrict__ memsl, const u16* __restrict__ hbf,
                                                 u16* __restrict__ cbf){
  int idx = blockIdx.x * 256 + threadIdx.x;       // 0 .. 4M-1
  u16 v;
  if (idx < 2097152) v = f2bf(memsl[idx]);
  else               v = hbf[idx - 2097152];
  cbf[idx] = v;
}

// ---------------- bf16 MFMA GEMM: C[M,N] = A[M,K] @ B[K,N] (+bias)(+relu) ----------------
__global__ __launch_bounds__(256) void gemm_bf16(
    const u16* __restrict__ A, const u16* __restrict__ B,
    const float* __restrict__ bias, float* __restrict__ C, u16* __restrict__ Cbf,
    int M, int N, int K, int relu)
{
  __shared__ u16 sA[128 * 40];    // [row][k], stride 40 (pad 8)
  __shared__ u16 sBt[128 * 40];   // [col][k], stride 40
  int tid = threadIdx.x;
  int lane = tid & 63, wid = tid >> 6;
  int wr = wid >> 1, wc = wid & 1;
  int m0 = blockIdx.y << 7, n0 = blockIdx.x << 7;

  f32x4 acc[4][4];
#pragma unroll
  for (int i = 0; i < 4; ++i)
#pragma unroll
    for (int j = 0; j < 4; ++j) acc[i][j] = (f32x4)(0.0f);

  int arow = tid >> 2;            // 0..63
  int acol = (tid & 3) << 3;      // 0,8,16,24
  int bn = tid & 127;             // B col within tile
  int bkh = (tid >> 7) << 4;      // 0 or 16

  const int laneck = (lane >> 4) << 3;  // k base 0,8,16,24
  const int lanecr = lane & 15;

  for (int k0 = 0; k0 < K; k0 += 32){
    u16x8 va0 = *(const u16x8*)(A + (size_t)(m0 + arow) * K + k0 + acol);
    u16x8 va1 = *(const u16x8*)(A + (size_t)(m0 + arow + 64) * K + k0 + acol);
    u16x8 vb0, vb1;
#pragma unroll
    for (int j = 0; j < 8; ++j){
      vb0[j] = B[(size_t)(k0 + bkh + j) * N + n0 + bn];
      vb1[j] = B[(size_t)(k0 + bkh + 8 + j) * N + n0 + bn];
    }
    *(u16x8*)(&sA[arow * 40 + acol]) = va0;
    *(u16x8*)(&sA[(arow + 64) * 40 + acol]) = va1;
    *(u16x8*)(&sBt[bn * 40 + bkh]) = vb0;
    *(u16x8*)(&sBt[bn * 40 + bkh + 8]) = vb1;
    __syncthreads();

    const u16* pa = sA + (wr << 6) * 40 + lanecr * 40 + laneck;
    const u16* pb = sBt + (wc << 6) * 40 + lanecr * 40 + laneck;
    bf16x8 af[4], bfv[4];
#pragma unroll
    for (int i = 0; i < 4; ++i){
      af[i]  = *(const bf16x8*)(pa + i * 16 * 40);
      bfv[i] = *(const bf16x8*)(pb + i * 16 * 40);
    }
#pragma unroll
    for (int mi = 0; mi < 4; ++mi)
#pragma unroll
      for (int ni = 0; ni < 4; ++ni)
        acc[mi][ni] = __builtin_amdgcn_mfma_f32_16x16x32_bf16(af[mi], bfv[ni], acc[mi][ni], 0, 0, 0);
    __syncthreads();
  }

  int colf = lane & 15, rowf = (lane >> 4) << 2;
#pragma unroll
  for (int ni = 0; ni < 4; ++ni){
    int cg = n0 + (wc << 6) + ni * 16 + colf;
    float bv = bias ? bias[cg] : 0.0f;
#pragma unroll
    for (int mi = 0; mi < 4; ++mi){
      int rg = m0 + (wr << 6) + mi * 16 + rowf;
#pragma unroll
      for (int r = 0; r < 4; ++r){
        float val = acc[mi][ni][r] + bv;
        if (relu) val = fmaxf(val, 0.0f);
        size_t o = (size_t)(rg + r) * N + cg;
        if (C)   C[o]   = val;
        if (Cbf) Cbf[o] = f2bf(val);
      }
    }
  }
}

// ---------------- kv[klen*bsz, 2048] -> kT/vT [b][n][d][j] ----------------
__global__ __launch_bounds__(256) void transpose_kv(const float* __restrict__ kv,
                                                    float* __restrict__ kT, float* __restrict__ vT){
  int idx = blockIdx.x * 256 + threadIdx.x;   // 0 .. 8.4M-1
  int row = idx >> 11, col = idx & 2047;      // row = j*4+b
  int j = row >> 2, b = row & 3, n = col >> 7, dd = col & 127;
  float v = kv[idx];
  size_t o = ((size_t)(((b << 4) + n) << 6) + (dd & 63)) * 1024 + j;
  if (dd < 64) kT[o] = v;
  else         vT[o] = v;
}

// ---------------- attention: wave per (b,n,i) row, two-pass softmax ----------------
__global__ __launch_bounds__(256) void flash_attn(
    const float* __restrict__ q, const float* __restrict__ kT,
    const float* __restrict__ vT, u16* __restrict__ attnbf)
{
  int wid = threadIdx.x >> 6, lane = threadIdx.x & 63;
  int ridx = (blockIdx.x << 2) + wid;         // (b,n,i): block shares (b,n)
  int i = ridx & 511, n = (ridx >> 9) & 15, b = ridx >> 13;

  const float* qrow = q + ((size_t)((i << 2) + b) << 10) + (n << 6);
  float qr[64];
#pragma unroll
  for (int d = 0; d < 64; ++d) qr[d] = qrow[d] * 0.125f;   // 1/sqrt(64)

  const float* kbase = kT + ((size_t)(((b << 4) + n) << 6) << 10);
  const float* vbase = vT + ((size_t)(((b << 4) + n) << 6) << 10);

  int jmax = i + 512;
  float sv[16];
#pragma unroll
  for (int t = 0; t < 16; ++t){
    int j = (t << 6) + lane;
    float s = 0.0f;
#pragma unroll
    for (int d = 0; d < 64; ++d) s = fmaf(qr[d], kbase[((size_t)d << 10) + j], s);
    sv[t] = (j <= jmax) ? s : -1e30f;
  }
  float m = -1e30f;
#pragma unroll
  for (int t = 0; t < 16; ++t) m = fmaxf(m, sv[t]);
#pragma unroll
  for (int off = 32; off; off >>= 1) m = fmaxf(m, __shfl_xor(m, off));
  float p[16]; float l = 0.0f;
#pragma unroll
  for (int t = 0; t < 16; ++t){ float e = __expf(sv[t] - m); p[t] = e; l += e; }
#pragma unroll
  for (int off = 32; off; off >>= 1) l += __shfl_xor(l, off);
  float inv = 1.0f / l;

  float o = 0.0f;
  for (int d = 0; d < 64; ++d){
    const float* vrow = vbase + ((size_t)d << 10) + lane;
    float part = 0.0f;
#pragma unroll
    for (int t = 0; t < 16; ++t) part = fmaf(p[t], vrow[t << 6], part);
#pragma unroll
    for (int off = 32; off; off >>= 1) part += __shfl_xor(part, off);
    if (d == lane) o = part;
  }
  attnbf[((size_t)((i << 2) + b) << 10) + (n << 6) + lane] = f2bf(o * inv);
}

// ---------------- residual + layernorm (block per row of 1024) ----------------
__global__ __launch_bounds__(256) void ln_k(const float* res, const float* __restrict__ x,
                                            const float* __restrict__ g, const float* __restrict__ bta,
                                            float* hout, u16* __restrict__ hbf)
{
  int row = blockIdx.x, tid = threadIdx.x;
  const float* rr = res + ((size_t)row << 10);
  const float* xr = x + ((size_t)row << 10);
  float v[4]; float s = 0.0f, s2 = 0.0f;
#pragma unroll
  for (int k = 0; k < 4; ++k){
    int d = tid + (k << 8);
    float t = rr[d] + xr[d];
    v[k] = t; s += t; s2 += t * t;
  }
#pragma unroll
  for (int off = 32; off; off >>= 1){ s += __shfl_xor(s, off); s2 += __shfl_xor(s2, off); }
  __shared__ float ps[8];
  int wid = tid >> 6, lane = tid & 63;
  if (lane == 0){ ps[wid] = s; ps[wid + 4] = s2; }
  __syncthreads();
  s  = ps[0] + ps[1] + ps[2] + ps[3];
  s2 = ps[4] + ps[5] + ps[6] + ps[7];
  float mu = s * 0.0009765625f;
  float var = s2 * 0.0009765625f - mu * mu;
  float rstd = rsqrtf(var + 1e-5f);
  float* ho = hout + ((size_t)row << 10);
  u16* hb = hbf + ((size_t)row << 10);
#pragma unroll
  for (int k = 0; k < 4; ++k){
    int d = tid + (k << 8);
    float t = (v[k] - mu) * rstd * g[d] + bta[d];
    ho[d] = t; hb[d] = f2bf(t);
  }
}

__global__ __launch_bounds__(256) void copy_f32(const f32x4* __restrict__ src, f32x4* __restrict__ dst){
  size_t i = (size_t)blockIdx.x * 256 + threadIdx.x;
  dst[i] = src[i];
}

extern "C" void kernel_launch(void* const* d_in, const int* in_sizes, int n_in,
                              void* d_out, int out_size, void* d_ws, size_t ws_size,
                              hipStream_t stream)
{
  const int*   data = (const int*)  d_in[0];
  const float* mems = (const float*)d_in[1];
  const float* emb  = (const float*)d_in[2];
  const float* Wq   = (const float*)d_in[3];
  const float* Wkv  = (const float*)d_in[4];
  const float* Wo   = (const float*)d_in[5];
  const float* ln1g = (const float*)d_in[6];
  const float* ln1b = (const float*)d_in[7];
  const float* W1   = (const float*)d_in[8];
  const float* b1   = (const float*)d_in[9];
  const float* W2   = (const float*)d_in[10];
  const float* b2   = (const float*)d_in[11];
  const float* ln2g = (const float*)d_in[12];
  const float* ln2b = (const float*)d_in[13];
  float* out = (float*)d_out;

  char* ws = (char*)d_ws;
  size_t off = 0;
  auto alloc = [&](size_t bytes) -> char* {
    char* p = ws + off;
    off = (off + bytes + 255) & ~(size_t)255;
    return p;
  };

  u16*   wq_bf  = (u16*)  alloc((size_t)6 * 1024 * 1024 * 2);
  u16*   wkv_bf = (u16*)  alloc((size_t)6 * 1024 * 2048 * 2);
  u16*   wo_bf  = (u16*)  alloc((size_t)6 * 1024 * 1024 * 2);
  u16*   w1_bf  = (u16*)  alloc((size_t)6 * 1024 * 4096 * 2);
  u16*   w2_bf  = (u16*)  alloc((size_t)6 * 4096 * 1024 * 2);
  float* h      = (float*)alloc((size_t)2048 * 1024 * 4);
  u16*   hbf    = (u16*)  alloc((size_t)2048 * 1024 * 2);
  u16*   cbf    = (u16*)  alloc((size_t)4096 * 1024 * 2);
  float* qf     = (float*)alloc((size_t)2048 * 1024 * 4);
  float* kvf    = (float*)alloc((size_t)4096 * 2048 * 4);
  float* kT     = (float*)alloc((size_t)64 * 64 * 1024 * 4);
  float* vT     = (float*)alloc((size_t)64 * 64 * 1024 * 4);
  u16*   attnbf = (u16*)  alloc((size_t)2048 * 1024 * 2);
  float* of_    = (float*)alloc((size_t)2048 * 1024 * 4);
  u16*   f1bf   = (u16*)  alloc((size_t)2048 * 4096 * 2);
  float* f2f    = (float*)alloc((size_t)2048 * 1024 * 4);

  // weights -> bf16 (once per call; deterministic)
  conv_bf16<<<6144,  256, 0, stream>>>(Wq,  wq_bf);
  conv_bf16<<<12288, 256, 0, stream>>>(Wkv, wkv_bf);
  conv_bf16<<<6144,  256, 0, stream>>>(Wo,  wo_bf);
  conv_bf16<<<24576, 256, 0, stream>>>(W1,  w1_bf);
  conv_bf16<<<24576, 256, 0, stream>>>(W2,  w2_bf);
  embed_k<<<8192, 256, 0, stream>>>(data, emb, h, hbf);

  for (int l = 0; l < 6; ++l){
    build_c_k<<<16384, 256, 0, stream>>>(mems + (size_t)l * 2048 * 1024, hbf, cbf);
    gemm_bf16<<<dim3(8, 16),  256, 0, stream>>>(hbf, wq_bf  + (size_t)l * 1024 * 1024, nullptr, qf,  nullptr, 2048, 1024, 1024, 0);
    gemm_bf16<<<dim3(16, 32), 256, 0, stream>>>(cbf, wkv_bf + (size_t)l * 1024 * 2048, nullptr, kvf, nullptr, 4096, 2048, 1024, 0);
    transpose_kv<<<32768, 256, 0, stream>>>(kvf, kT, vT);
    flash_attn<<<8192, 256, 0, stream>>>(qf, kT, vT, attnbf);
    gemm_bf16<<<dim3(8, 16),  256, 0, stream>>>(attnbf, wo_bf + (size_t)l * 1024 * 1024, nullptr, of_, nullptr, 2048, 1024, 1024, 0);
    ln_k<<<2048, 256, 0, stream>>>(h, of_, ln1g + l * 1024, ln1b + l * 1024, h, hbf);
    gemm_bf16<<<dim3(32, 16), 256, 0, stream>>>(hbf,  w1_bf + (size_t)l * 1024 * 4096, b1 + (size_t)l * 4096, nullptr, f1bf, 2048, 4096, 1024, 1);
    gemm_bf16<<<dim3(8, 16),  256, 0, stream>>>(f1bf, w2_bf + (size_t)l * 4096 * 1024, b2 + (size_t)l * 1024, f2f, nullptr, 2048, 1024, 4096, 0);
    ln_k<<<2048, 256, 0, stream>>>(h, f2f, ln2g + l * 1024, ln2b + l * 1024, h, hbf);
  }
  copy_f32<<<2048, 256, 0, stream>>>((const f32x4*)h, (f32x4*)out);
}

// Round 2
// 2491.291 us; speedup vs baseline: 9.7958x; 9.7958x over previous
//
#include <hip/hip_runtime.h>

typedef unsigned short u16;
typedef unsigned int u32;
typedef __bf16 bf16x8 __attribute__((ext_vector_type(8)));
typedef float f32x4 __attribute__((ext_vector_type(4)));
typedef u16 u16x8 __attribute__((ext_vector_type(8)));
typedef u16 u16x4 __attribute__((ext_vector_type(4)));
typedef u32 u32x4 __attribute__((ext_vector_type(4)));

__device__ __forceinline__ u16 f2bf(float f){
  unsigned u = __float_as_uint(f);
  u += 0x7FFFu + ((u >> 16) & 1u);   // RNE
  return (u16)(u >> 16);
}
__device__ __forceinline__ u32 pack2bf(float a, float b){
  return (u32)f2bf(a) | ((u32)f2bf(b) << 16);
}

// ---------------- weight f32 -> bf16 (4 elems/thread) ----------------
__global__ __launch_bounds__(256) void conv_bf16(const float* __restrict__ src, u16* __restrict__ dst){
  size_t i = ((size_t)blockIdx.x * 256 + threadIdx.x) * 4;
  f32x4 v = *(const f32x4*)(src + i);
  u16x4 o;
#pragma unroll
  for (int j = 0; j < 4; ++j) o[j] = f2bf(v[j]);
  *(u16x4*)(dst + i) = o;
}

// ---------------- embedding + positional encoding ----------------
__global__ __launch_bounds__(256) void embed_k(const int* __restrict__ data, const float* __restrict__ emb,
                                               float* __restrict__ h, u16* __restrict__ hbf){
  int idx = blockIdx.x * 256 + threadIdx.x;       // 0 .. 2M-1
  int r = idx >> 10, d = idx & 1023;              // r = i*4+b
  int i = r >> 2;
  int e = data[r];
  float val = emb[(size_t)e * 1024 + d] * 32.0f;  // sqrt(1024)
  float pos = (float)(511 - i);
  int t = d & 511;
  float freq = powf(10000.0f, -(float)t * (1.0f / 512.0f));
  float ang = pos * freq;
  val += (d < 512) ? sinf(ang) : cosf(ang);
  h[idx] = val;
  hbf[idx] = f2bf(val);
}

// ---------------- build concat(mems[l], h) in bf16 ----------------
__global__ __launch_bounds__(256) void build_c_k(const float* __restrict__ memsl, const u16* __restrict__ hbf,
                                                 u16* __restrict__ cbf){
  int idx = blockIdx.x * 256 + threadIdx.x;       // 0 .. 4M-1
  u16 v;
  if (idx < 2097152) v = f2bf(memsl[idx]);
  else               v = hbf[idx - 2097152];
  cbf[idx] = v;
}

// ---------------- bf16 MFMA GEMM: C[M,N] = A[M,K] @ B[K,N] (+bias)(+relu) ----------------
__global__ __launch_bounds__(256) void gemm_bf16(
    const u16* __restrict__ A, const u16* __restrict__ B,
    const float* __restrict__ bias, float* __restrict__ C, u16* __restrict__ Cbf,
    int M, int N, int K, int relu)
{
  __shared__ u16 sA[128 * 40];    // [row][k], stride 40 (pad 8)
  __shared__ u16 sBt[128 * 40];   // [col][k], stride 40
  int tid = threadIdx.x;
  int lane = tid & 63, wid = tid >> 6;
  int wr = wid >> 1, wc = wid & 1;
  int m0 = blockIdx.y << 7, n0 = blockIdx.x << 7;

  f32x4 acc[4][4];
#pragma unroll
  for (int i = 0; i < 4; ++i)
#pragma unroll
    for (int j = 0; j < 4; ++j) acc[i][j] = (f32x4)(0.0f);

  int arow = tid >> 2;            // 0..63
  int acol = (tid & 3) << 3;      // 0,8,16,24
  int bn = tid & 127;             // B col within tile
  int bkh = (tid >> 7) << 4;      // 0 or 16

  const int laneck = (lane >> 4) << 3;  // k base 0,8,16,24
  const int lanecr = lane & 15;

  for (int k0 = 0; k0 < K; k0 += 32){
    u16x8 va0 = *(const u16x8*)(A + (size_t)(m0 + arow) * K + k0 + acol);
    u16x8 va1 = *(const u16x8*)(A + (size_t)(m0 + arow + 64) * K + k0 + acol);
    u16x8 vb0, vb1;
#pragma unroll
    for (int j = 0; j < 8; ++j){
      vb0[j] = B[(size_t)(k0 + bkh + j) * N + n0 + bn];
      vb1[j] = B[(size_t)(k0 + bkh + 8 + j) * N + n0 + bn];
    }
    *(u16x8*)(&sA[arow * 40 + acol]) = va0;
    *(u16x8*)(&sA[(arow + 64) * 40 + acol]) = va1;
    *(u16x8*)(&sBt[bn * 40 + bkh]) = vb0;
    *(u16x8*)(&sBt[bn * 40 + bkh + 8]) = vb1;
    __syncthreads();

    const u16* pa = sA + (wr << 6) * 40 + lanecr * 40 + laneck;
    const u16* pb = sBt + (wc << 6) * 40 + lanecr * 40 + laneck;
    bf16x8 af[4], bfv[4];
#pragma unroll
    for (int i = 0; i < 4; ++i){
      af[i]  = *(const bf16x8*)(pa + i * 16 * 40);
      bfv[i] = *(const bf16x8*)(pb + i * 16 * 40);
    }
#pragma unroll
    for (int mi = 0; mi < 4; ++mi)
#pragma unroll
      for (int ni = 0; ni < 4; ++ni)
        acc[mi][ni] = __builtin_amdgcn_mfma_f32_16x16x32_bf16(af[mi], bfv[ni], acc[mi][ni], 0, 0, 0);
    __syncthreads();
  }

  int colf = lane & 15, rowf = (lane >> 4) << 2;
#pragma unroll
  for (int ni = 0; ni < 4; ++ni){
    int cg = n0 + (wc << 6) + ni * 16 + colf;
    float bv = bias ? bias[cg] : 0.0f;
#pragma unroll
    for (int mi = 0; mi < 4; ++mi){
      int rg = m0 + (wr << 6) + mi * 16 + rowf;
#pragma unroll
      for (int r = 0; r < 4; ++r){
        float val = acc[mi][ni][r] + bv;
        if (relu) val = fmaxf(val, 0.0f);
        size_t o = (size_t)(rg + r) * N + cg;
        if (C)   C[o]   = val;
        if (Cbf) Cbf[o] = f2bf(val);
      }
    }
  }
}

// ---------------- V transpose: kvbf [(j*4+b)][n*128+64+d] -> vtbf [bn][d][j] ----------------
__global__ __launch_bounds__(256) void vtrans(const u16* __restrict__ kvbf, u16* __restrict__ vtbf){
  __shared__ u16 s[64 * 68];
  int jt = blockIdx.x, bnp = blockIdx.y;
  int b = bnp >> 4, n = bnp & 15;
  int t = threadIdx.x;
  int j0 = jt << 6;
#pragma unroll
  for (int rr = 0; rr < 16; ++rr){
    int idx = rr * 256 + t;
    int jl = idx >> 6, dd = idx & 63;
    s[jl * 68 + dd] = kvbf[((size_t)((j0 + jl) * 4 + b) << 11) + n * 128 + 64 + dd];
  }
  __syncthreads();
#pragma unroll
  for (int ww = 0; ww < 16; ++ww){
    int idx = ww * 256 + t;
    int dd = idx >> 6, jl = idx & 63;
    vtbf[((size_t)(bnp * 64 + dd) << 10) + j0 + jl] = s[jl * 68 + dd];
  }
}

// ---------------- MFMA flash attention ----------------
// Wave handles 16 q-rows of one (b,n). S^T = mfma(K, Q): lane (t=lane&15, g=lane>>4)
// holds S^T[j = jf*16+g*4+r][i = i0+t]. Softmax per i-column: shfl_xor 16/32.
// PV: O^T = mfma(V^T, P^T) with P^T B-frag built by register shuffles.
__global__ __launch_bounds__(256) void attn_mfma(
    const u16* __restrict__ qbf, const u16* __restrict__ kvbf,
    const u16* __restrict__ vtbf, u16* __restrict__ attnbf)
{
  int tid = threadIdx.x, lane = tid & 63, wid = tid >> 6;
  int g = lane >> 4, t = lane & 15;
  int qt = blockIdx.x, bnp = blockIdx.y;
  int b = bnp >> 4, n = bnp & 15;
  int i0 = qt * 64 + wid * 16;
  int i = i0 + t;

  union Cvt { u32x4 u; bf16x8 v; };

  // Q fragments (B-operand), k-slices of 32 d each
  bf16x8 qfrag[2];
#pragma unroll
  for (int ks = 0; ks < 2; ++ks)
    qfrag[ks] = *(const bf16x8*)(qbf + ((size_t)(i * 4 + b) << 10) + n * 64 + ks * 32 + g * 8);

  f32x4 oacc[4];
#pragma unroll
  for (int df = 0; df < 4; ++df) oacc[df] = (f32x4)(0.0f);
  float mrun = -1e30f, lrun = 0.0f;

  int nt = ((i0 + 527) >> 6) + 1;      // tiles with j0 <= i0+15+512
  for (int kt = 0; kt < nt; ++kt){
    int j0 = kt << 6;
    f32x4 sacc[4];
#pragma unroll
    for (int jf = 0; jf < 4; ++jf) sacc[jf] = (f32x4)(0.0f);
#pragma unroll
    for (int ks = 0; ks < 2; ++ks){
#pragma unroll
      for (int jf = 0; jf < 4; ++jf){
        int j = j0 + jf * 16 + t;
        bf16x8 kf = *(const bf16x8*)(kvbf + ((size_t)(j * 4 + b) << 11) + n * 128 + ks * 32 + g * 8);
        sacc[jf] = __builtin_amdgcn_mfma_f32_16x16x32_bf16(kf, qfrag[ks], sacc[jf], 0, 0, 0);
      }
    }
    // extract + scale + mask + tile max
    bool part = (j0 + 63 > i0 + 512);
    float ps[4][4];
    float tmax = -1e30f;
#pragma unroll
    for (int jf = 0; jf < 4; ++jf)
#pragma unroll
      for (int r = 0; r < 4; ++r){
        float s = sacc[jf][r] * 0.125f;
        if (part && (j0 + jf * 16 + g * 4 + r > i + 512)) s = -1e30f;
        ps[jf][r] = s;
        tmax = fmaxf(tmax, s);
      }
    tmax = fmaxf(tmax, __shfl_xor(tmax, 16));
    tmax = fmaxf(tmax, __shfl_xor(tmax, 32));
    float mnew = fmaxf(mrun, tmax);
    float sc = __expf(mrun - mnew);
    mrun = mnew;
    lrun *= sc;
    u32 pk0[2], pk1[2], pk2[2], pk3[2];   // pk[jf][h], named to keep static indexing
    {
      float e0, e1, e2, e3;
#define DO_JF(PK, JF) \
      e0 = __expf(ps[JF][0] - mnew); e1 = __expf(ps[JF][1] - mnew); \
      e2 = __expf(ps[JF][2] - mnew); e3 = __expf(ps[JF][3] - mnew); \
      lrun += (e0 + e1) + (e2 + e3); \
      PK[0] = pack2bf(e0, e1); PK[1] = pack2bf(e2, e3);
      DO_JF(pk0, 0) DO_JF(pk1, 1) DO_JF(pk2, 2) DO_JF(pk3, 3)
#undef DO_JF
    }
#pragma unroll
    for (int df = 0; df < 4; ++df)
#pragma unroll
      for (int r = 0; r < 4; ++r) oacc[df][r] *= sc;

    // PV: build P^T B-frag via shuffles (lane g needs j = ks*32 + g*8 + e, col i=t)
    int srcA = t + 16 * ((2 * g) & 3);
    int srcB = t + 16 * ((2 * g + 1) & 3);
    bool ghi = (g >= 2);               // jf_s = 2ks + (g>>1)
#pragma unroll
    for (int ks = 0; ks < 2; ++ks){
      u32 w0a, w1a, w2a, w3a, w0b, w1b, w2b, w3b;
      if (ks == 0){
        w0a = __shfl((int)pk0[0], srcA); w1a = __shfl((int)pk0[1], srcA);
        w2a = __shfl((int)pk0[0], srcB); w3a = __shfl((int)pk0[1], srcB);
        w0b = __shfl((int)pk1[0], srcA); w1b = __shfl((int)pk1[1], srcA);
        w2b = __shfl((int)pk1[0], srcB); w3b = __shfl((int)pk1[1], srcB);
      } else {
        w0a = __shfl((int)pk2[0], srcA); w1a = __shfl((int)pk2[1], srcA);
        w2a = __shfl((int)pk2[0], srcB); w3a = __shfl((int)pk2[1], srcB);
        w0b = __shfl((int)pk3[0], srcA); w1b = __shfl((int)pk3[1], srcA);
        w2b = __shfl((int)pk3[0], srcB); w3b = __shfl((int)pk3[1], srcB);
      }
      Cvt c;
      c.u[0] = ghi ? w0b : w0a;
      c.u[1] = ghi ? w1b : w1a;
      c.u[2] = ghi ? w2b : w2a;
      c.u[3] = ghi ? w3b : w3a;
      bf16x8 pf = c.v;
#pragma unroll
      for (int df = 0; df < 4; ++df){
        bf16x8 vf = *(const bf16x8*)(vtbf + ((size_t)(bnp * 64 + df * 16 + t) << 10) + j0 + ks * 32 + g * 8);
        oacc[df] = __builtin_amdgcn_mfma_f32_16x16x32_bf16(vf, pf, oacc[df], 0, 0, 0);
      }
    }
  }
  lrun += __shfl_xor(lrun, 16);
  lrun += __shfl_xor(lrun, 32);
  float inv = 1.0f / lrun;

  u16* orow = attnbf + ((size_t)(i * 4 + b) << 10) + n * 64;
#pragma unroll
  for (int df = 0; df < 4; ++df){
#pragma unroll
    for (int h = 0; h < 2; ++h){
      u32 w = pack2bf(oacc[df][2 * h] * inv, oacc[df][2 * h + 1] * inv);
      *(u32*)(orow + df * 16 + g * 4 + 2 * h) = w;
    }
  }
}

// ---------------- residual + layernorm (block per row of 1024) ----------------
__global__ __launch_bounds__(256) void ln_k(const float* res, const float* __restrict__ x,
                                            const float* __restrict__ g, const float* __restrict__ bta,
                                            float* hout, u16* __restrict__ hbf)
{
  int row = blockIdx.x, tid = threadIdx.x;
  const float* rr = res + ((size_t)row << 10);
  const float* xr = x + ((size_t)row << 10);
  float v[4]; float s = 0.0f, s2 = 0.0f;
#pragma unroll
  for (int k = 0; k < 4; ++k){
    int d = tid + (k << 8);
    float t = rr[d] + xr[d];
    v[k] = t; s += t; s2 += t * t;
  }
#pragma unroll
  for (int off = 32; off; off >>= 1){ s += __shfl_xor(s, off); s2 += __shfl_xor(s2, off); }
  __shared__ float ps[8];
  int wid = tid >> 6, lane = tid & 63;
  if (lane == 0){ ps[wid] = s; ps[wid + 4] = s2; }
  __syncthreads();
  s  = ps[0] + ps[1] + ps[2] + ps[3];
  s2 = ps[4] + ps[5] + ps[6] + ps[7];
  float mu = s * 0.0009765625f;
  float var = s2 * 0.0009765625f - mu * mu;
  float rstd = rsqrtf(var + 1e-5f);
  float* ho = hout + ((size_t)row << 10);
  u16* hb = hbf + ((size_t)row << 10);
#pragma unroll
  for (int k = 0; k < 4; ++k){
    int d = tid + (k << 8);
    float t = (v[k] - mu) * rstd * g[d] + bta[d];
    ho[d] = t; hb[d] = f2bf(t);
  }
}

__global__ __launch_bounds__(256) void copy_f32(const f32x4* __restrict__ src, f32x4* __restrict__ dst){
  size_t i = (size_t)blockIdx.x * 256 + threadIdx.x;
  dst[i] = src[i];
}

extern "C" void kernel_launch(void* const* d_in, const int* in_sizes, int n_in,
                              void* d_out, int out_size, void* d_ws, size_t ws_size,
                              hipStream_t stream)
{
  const int*   data = (const int*)  d_in[0];
  const float* mems = (const float*)d_in[1];
  const float* emb  = (const float*)d_in[2];
  const float* Wq   = (const float*)d_in[3];
  const float* Wkv  = (const float*)d_in[4];
  const float* Wo   = (const float*)d_in[5];
  const float* ln1g = (const float*)d_in[6];
  const float* ln1b = (const float*)d_in[7];
  const float* W1   = (const float*)d_in[8];
  const float* b1   = (const float*)d_in[9];
  const float* W2   = (const float*)d_in[10];
  const float* b2   = (const float*)d_in[11];
  const float* ln2g = (const float*)d_in[12];
  const float* ln2b = (const float*)d_in[13];
  float* out = (float*)d_out;

  char* ws = (char*)d_ws;
  size_t off = 0;
  auto alloc = [&](size_t bytes) -> char* {
    char* p = ws + off;
    off = (off + bytes + 255) & ~(size_t)255;
    return p;
  };

  u16*   wq_bf  = (u16*)  alloc((size_t)6 * 1024 * 1024 * 2);
  u16*   wkv_bf = (u16*)  alloc((size_t)6 * 1024 * 2048 * 2);
  u16*   wo_bf  = (u16*)  alloc((size_t)6 * 1024 * 1024 * 2);
  u16*   w1_bf  = (u16*)  alloc((size_t)6 * 1024 * 4096 * 2);
  u16*   w2_bf  = (u16*)  alloc((size_t)6 * 4096 * 1024 * 2);
  float* h      = (float*)alloc((size_t)2048 * 1024 * 4);
  u16*   hbf    = (u16*)  alloc((size_t)2048 * 1024 * 2);
  u16*   cbf    = (u16*)  alloc((size_t)4096 * 1024 * 2);
  u16*   qbf    = (u16*)  alloc((size_t)2048 * 1024 * 2);
  u16*   kvbf   = (u16*)  alloc((size_t)4096 * 2048 * 2);
  u16*   vtbf   = (u16*)  alloc((size_t)64 * 64 * 1024 * 2);
  u16*   attnbf = (u16*)  alloc((size_t)2048 * 1024 * 2);
  float* of_    = (float*)alloc((size_t)2048 * 1024 * 4);
  u16*   f1bf   = (u16*)  alloc((size_t)2048 * 4096 * 2);
  float* f2f    = (float*)alloc((size_t)2048 * 1024 * 4);

  // weights -> bf16 (once per call; deterministic)
  conv_bf16<<<6144,  256, 0, stream>>>(Wq,  wq_bf);
  conv_bf16<<<12288, 256, 0, stream>>>(Wkv, wkv_bf);
  conv_bf16<<<6144,  256, 0, stream>>>(Wo,  wo_bf);
  conv_bf16<<<24576, 256, 0, stream>>>(W1,  w1_bf);
  conv_bf16<<<24576, 256, 0, stream>>>(W2,  w2_bf);
  embed_k<<<8192, 256, 0, stream>>>(data, emb, h, hbf);

  for (int l = 0; l < 6; ++l){
    build_c_k<<<16384, 256, 0, stream>>>(mems + (size_t)l * 2048 * 1024, hbf, cbf);
    gemm_bf16<<<dim3(8, 16),  256, 0, stream>>>(hbf, wq_bf  + (size_t)l * 1024 * 1024, nullptr, nullptr, qbf, 2048, 1024, 1024, 0);
    gemm_bf16<<<dim3(16, 32), 256, 0, stream>>>(cbf, wkv_bf + (size_t)l * 1024 * 2048, nullptr, nullptr, kvbf, 4096, 2048, 1024, 0);
    vtrans<<<dim3(16, 64), 256, 0, stream>>>(kvbf, vtbf);
    attn_mfma<<<dim3(8, 64), 256, 0, stream>>>(qbf, kvbf, vtbf, attnbf);
    gemm_bf16<<<dim3(8, 16),  256, 0, stream>>>(attnbf, wo_bf + (size_t)l * 1024 * 1024, nullptr, of_, nullptr, 2048, 1024, 1024, 0);
    ln_k<<<2048, 256, 0, stream>>>(h, of_, ln1g + l * 1024, ln1b + l * 1024, h, hbf);
    gemm_bf16<<<dim3(32, 16), 256, 0, stream>>>(hbf,  w1_bf + (size_t)l * 1024 * 4096, b1 + (size_t)l * 4096, nullptr, f1bf, 2048, 4096, 1024, 1);
    gemm_bf16<<<dim3(8, 16),  256, 0, stream>>>(f1bf, w2_bf + (size_t)l * 4096 * 1024, b2 + (size_t)l * 1024, f2f, nullptr, 2048, 1024, 4096, 0);
    ln_k<<<2048, 256, 0, stream>>>(h, f2f, ln2g + l * 1024, ln2b + l * 1024, h, hbf);
  }
  copy_f32<<<2048, 256, 0, stream>>>((const f32x4*)h, (f32x4*)out);
}

// Round 3
// 1858.970 us; speedup vs baseline: 13.1278x; 1.3401x over previous
//
#include <hip/hip_runtime.h>

typedef unsigned short u16;
typedef unsigned int u32;
typedef __bf16 bf16x8 __attribute__((ext_vector_type(8)));
typedef float f32x4 __attribute__((ext_vector_type(4)));
typedef u16 u16x8 __attribute__((ext_vector_type(8)));
typedef u16 u16x4 __attribute__((ext_vector_type(4)));
typedef u32 u32x4 __attribute__((ext_vector_type(4)));

__device__ __forceinline__ u16 f2bf(float f){
  unsigned u = __float_as_uint(f);
  u += 0x7FFFu + ((u >> 16) & 1u);   // RNE
  return (u16)(u >> 16);
}
__device__ __forceinline__ u32 pack2bf(float a, float b){
  return (u32)f2bf(a) | ((u32)f2bf(b) << 16);
}
__device__ __forceinline__ void gload16(const void* g, void* l){
  __builtin_amdgcn_global_load_lds(
      (const __attribute__((address_space(1))) void*)g,
      (__attribute__((address_space(3))) void*)l, 16, 0, 0);
}

// ---------------- weight f32 [K][N] -> bf16 [N][K] (transposing convert) ----------------
__global__ __launch_bounds__(256) void conv_bf16_t(const float* __restrict__ src, u16* __restrict__ dst,
                                                   int K, int N){
  __shared__ u16 s[64 * 68];
  size_t lo = (size_t)blockIdx.z * K * N;
  int n0 = blockIdx.x << 6, k0 = blockIdx.y << 6;
  int t = threadIdx.x;
#pragma unroll
  for (int p = 0; p < 16; ++p){
    int idx = p * 256 + t;
    int kl = idx >> 6, nl = idx & 63;
    s[nl * 68 + kl] = f2bf(src[lo + (size_t)(k0 + kl) * N + n0 + nl]);
  }
  __syncthreads();
#pragma unroll
  for (int p = 0; p < 16; ++p){
    int idx = p * 256 + t;
    int nl = idx >> 6, kl = idx & 63;
    dst[lo + (size_t)(n0 + nl) * K + k0 + kl] = s[nl * 68 + kl];
  }
}

// ---------------- embedding + positional encoding ----------------
__global__ __launch_bounds__(256) void embed_k(const int* __restrict__ data, const float* __restrict__ emb,
                                               float* __restrict__ h, u16* __restrict__ hbf){
  int idx = blockIdx.x * 256 + threadIdx.x;       // 0 .. 2M-1
  int r = idx >> 10, d = idx & 1023;              // r = i*4+b
  int i = r >> 2;
  int e = data[r];
  float val = emb[(size_t)e * 1024 + d] * 32.0f;  // sqrt(1024)
  float pos = (float)(511 - i);
  int t = d & 511;
  float freq = powf(10000.0f, -(float)t * (1.0f / 512.0f));
  float ang = pos * freq;
  val += (d < 512) ? sinf(ang) : cosf(ang);
  h[idx] = val;
  hbf[idx] = f2bf(val);
}

// ---------------- build concat(mems[l], h) in bf16 ----------------
__global__ __launch_bounds__(256) void build_c_k(const float* __restrict__ memsl, const u16* __restrict__ hbf,
                                                 u16* __restrict__ cbf){
  int idx = blockIdx.x * 256 + threadIdx.x;       // 0 .. 4M-1
  u16 v;
  if (idx < 2097152) v = f2bf(memsl[idx]);
  else               v = hbf[idx - 2097152];
  cbf[idx] = v;
}

// ---------------- bf16 MFMA GEMM: C[M,N] = A[M,K] @ Bt[N,K]^T (+bias)(+relu) ----------------
// m97 structure: linear LDS tiles, global_load_lds width-16 staging, ds_read_b128 frags.
template<int BM>
__global__ __launch_bounds__(256) void gemm_bt(
    const u16* __restrict__ A, const u16* __restrict__ Bt,
    const float* __restrict__ bias, float* __restrict__ C, u16* __restrict__ Cbf,
    int M, int N, int K, int relu)
{
  constexpr int MFR = BM / 32;            // A frags per wave (rows/16): 4 for 128, 2 for 64
  __shared__ __align__(16) u16 sA[BM * 32];
  __shared__ __align__(16) u16 sB[128 * 32];
  int tid = threadIdx.x, lane = tid & 63;
  int wr = (tid >> 7) & 1, wc = (tid >> 6) & 1;   // 2x2 wave grid
  int m0 = blockIdx.y * BM, n0 = blockIdx.x << 7;

  f32x4 acc[MFR][4];
#pragma unroll
  for (int i = 0; i < MFR; ++i)
#pragma unroll
    for (int j = 0; j < 4; ++j) acc[i][j] = (f32x4)(0.0f);

  int srow = tid >> 2;                    // 0..63
  int scol = (tid & 3) << 3;              // k-element offset 0,8,16,24
  const u16* Ab = A + (size_t)(m0 + srow) * K + scol;
  const u16* Bb = Bt + (size_t)(n0 + srow) * K + scol;
  const size_t rstep = (size_t)K << 6;    // 64 rows

  const u16* pa = sA + (wr * (BM / 2) + (lane & 15)) * 32 + ((lane >> 4) << 3);
  const u16* pb = sB + (wc * 64 + (lane & 15)) * 32 + ((lane >> 4) << 3);

  for (int k0 = 0; k0 < K; k0 += 32){
#pragma unroll
    for (int c = 0; c < BM / 64; ++c)
      gload16(Ab + c * rstep + k0, (void*)&sA[c * 2048 + tid * 8]);
#pragma unroll
    for (int c = 0; c < 2; ++c)
      gload16(Bb + c * rstep + k0, (void*)&sB[c * 2048 + tid * 8]);
    __syncthreads();

    bf16x8 af[MFR], bfv[4];
#pragma unroll
    for (int mi = 0; mi < MFR; ++mi) af[mi] = *(const bf16x8*)(pa + mi * 16 * 32);
#pragma unroll
    for (int ni = 0; ni < 4; ++ni)   bfv[ni] = *(const bf16x8*)(pb + ni * 16 * 32);
#pragma unroll
    for (int mi = 0; mi < MFR; ++mi)
#pragma unroll
      for (int ni = 0; ni < 4; ++ni)
        acc[mi][ni] = __builtin_amdgcn_mfma_f32_16x16x32_bf16(af[mi], bfv[ni], acc[mi][ni], 0, 0, 0);
    __syncthreads();
  }

  int colf = lane & 15, rowf = (lane >> 4) << 2;
#pragma unroll
  for (int ni = 0; ni < 4; ++ni){
    int cg = n0 + (wc << 6) + ni * 16 + colf;
    float bv = bias ? bias[cg] : 0.0f;
#pragma unroll
    for (int mi = 0; mi < MFR; ++mi){
      int rg = m0 + wr * (BM / 2) + mi * 16 + rowf;
#pragma unroll
      for (int r = 0; r < 4; ++r){
        float val = acc[mi][ni][r] + bv;
        if (relu) val = fmaxf(val, 0.0f);
        size_t o = (size_t)(rg + r) * N + cg;
        if (C)   C[o]   = val;
        if (Cbf) Cbf[o] = f2bf(val);
      }
    }
  }
}

// ---------------- V transpose: kvbf [(j*4+b)][n*128+64+d] -> vtbf [bn][d][j] ----------------
__global__ __launch_bounds__(256) void vtrans(const u16* __restrict__ kvbf, u16* __restrict__ vtbf){
  __shared__ u16 s[64 * 68];
  int jt = blockIdx.x, bnp = blockIdx.y;
  int b = bnp >> 4, n = bnp & 15;
  int t = threadIdx.x;
  int j0 = jt << 6;
#pragma unroll
  for (int rr = 0; rr < 16; ++rr){
    int idx = rr * 256 + t;
    int jl = idx >> 6, dd = idx & 63;
    s[jl * 68 + dd] = kvbf[((size_t)((j0 + jl) * 4 + b) << 11) + n * 128 + 64 + dd];
  }
  __syncthreads();
#pragma unroll
  for (int ww = 0; ww < 16; ++ww){
    int idx = ww * 256 + t;
    int dd = idx >> 6, jl = idx & 63;
    vtbf[((size_t)(bnp * 64 + dd) << 10) + j0 + jl] = s[jl * 68 + dd];
  }
}

// ---------------- MFMA flash attention (unchanged, verified) ----------------
__global__ __launch_bounds__(256) void attn_mfma(
    const u16* __restrict__ qbf, const u16* __restrict__ kvbf,
    const u16* __restrict__ vtbf, u16* __restrict__ attnbf)
{
  int tid = threadIdx.x, lane = tid & 63, wid = tid >> 6;
  int g = lane >> 4, t = lane & 15;
  int qt = blockIdx.x, bnp = blockIdx.y;
  int b = bnp >> 4, n = bnp & 15;
  int i0 = qt * 64 + wid * 16;
  int i = i0 + t;

  union Cvt { u32x4 u; bf16x8 v; };

  bf16x8 qfrag[2];
#pragma unroll
  for (int ks = 0; ks < 2; ++ks)
    qfrag[ks] = *(const bf16x8*)(qbf + ((size_t)(i * 4 + b) << 10) + n * 64 + ks * 32 + g * 8);

  f32x4 oacc[4];
#pragma unroll
  for (int df = 0; df < 4; ++df) oacc[df] = (f32x4)(0.0f);
  float mrun = -1e30f, lrun = 0.0f;

  int nt = ((i0 + 527) >> 6) + 1;
  for (int kt = 0; kt < nt; ++kt){
    int j0 = kt << 6;
    f32x4 sacc[4];
#pragma unroll
    for (int jf = 0; jf < 4; ++jf) sacc[jf] = (f32x4)(0.0f);
#pragma unroll
    for (int ks = 0; ks < 2; ++ks){
#pragma unroll
      for (int jf = 0; jf < 4; ++jf){
        int j = j0 + jf * 16 + t;
        bf16x8 kf = *(const bf16x8*)(kvbf + ((size_t)(j * 4 + b) << 11) + n * 128 + ks * 32 + g * 8);
        sacc[jf] = __builtin_amdgcn_mfma_f32_16x16x32_bf16(kf, qfrag[ks], sacc[jf], 0, 0, 0);
      }
    }
    bool part = (j0 + 63 > i0 + 512);
    float ps[4][4];
    float tmax = -1e30f;
#pragma unroll
    for (int jf = 0; jf < 4; ++jf)
#pragma unroll
      for (int r = 0; r < 4; ++r){
        float s = sacc[jf][r] * 0.125f;
        if (part && (j0 + jf * 16 + g * 4 + r > i + 512)) s = -1e30f;
        ps[jf][r] = s;
        tmax = fmaxf(tmax, s);
      }
    tmax = fmaxf(tmax, __shfl_xor(tmax, 16));
    tmax = fmaxf(tmax, __shfl_xor(tmax, 32));
    float mnew = fmaxf(mrun, tmax);
    float sc = __expf(mrun - mnew);
    mrun = mnew;
    lrun *= sc;
    u32 pk0[2], pk1[2], pk2[2], pk3[2];
    {
      float e0, e1, e2, e3;
#define DO_JF(PK, JF) \
      e0 = __expf(ps[JF][0] - mnew); e1 = __expf(ps[JF][1] - mnew); \
      e2 = __expf(ps[JF][2] - mnew); e3 = __expf(ps[JF][3] - mnew); \
      lrun += (e0 + e1) + (e2 + e3); \
      PK[0] = pack2bf(e0, e1); PK[1] = pack2bf(e2, e3);
      DO_JF(pk0, 0) DO_JF(pk1, 1) DO_JF(pk2, 2) DO_JF(pk3, 3)
#undef DO_JF
    }
#pragma unroll
    for (int df = 0; df < 4; ++df)
#pragma unroll
      for (int r = 0; r < 4; ++r) oacc[df][r] *= sc;

    int srcA = t + 16 * ((2 * g) & 3);
    int srcB = t + 16 * ((2 * g + 1) & 3);
    bool ghi = (g >= 2);
#pragma unroll
    for (int ks = 0; ks < 2; ++ks){
      u32 w0a, w1a, w2a, w3a, w0b, w1b, w2b, w3b;
      if (ks == 0){
        w0a = __shfl((int)pk0[0], srcA); w1a = __shfl((int)pk0[1], srcA);
        w2a = __shfl((int)pk0[0], srcB); w3a = __shfl((int)pk0[1], srcB);
        w0b = __shfl((int)pk1[0], srcA); w1b = __shfl((int)pk1[1], srcA);
        w2b = __shfl((int)pk1[0], srcB); w3b = __shfl((int)pk1[1], srcB);
      } else {
        w0a = __shfl((int)pk2[0], srcA); w1a = __shfl((int)pk2[1], srcA);
        w2a = __shfl((int)pk2[0], srcB); w3a = __shfl((int)pk2[1], srcB);
        w0b = __shfl((int)pk3[0], srcA); w1b = __shfl((int)pk3[1], srcA);
        w2b = __shfl((int)pk3[0], srcB); w3b = __shfl((int)pk3[1], srcB);
      }
      Cvt c;
      c.u[0] = ghi ? w0b : w0a;
      c.u[1] = ghi ? w1b : w1a;
      c.u[2] = ghi ? w2b : w2a;
      c.u[3] = ghi ? w3b : w3a;
      bf16x8 pf = c.v;
#pragma unroll
      for (int df = 0; df < 4; ++df){
        bf16x8 vf = *(const bf16x8*)(vtbf + ((size_t)(bnp * 64 + df * 16 + t) << 10) + j0 + ks * 32 + g * 8);
        oacc[df] = __builtin_amdgcn_mfma_f32_16x16x32_bf16(vf, pf, oacc[df], 0, 0, 0);
      }
    }
  }
  lrun += __shfl_xor(lrun, 16);
  lrun += __shfl_xor(lrun, 32);
  float inv = 1.0f / lrun;

  u16* orow = attnbf + ((size_t)(i * 4 + b) << 10) + n * 64;
#pragma unroll
  for (int df = 0; df < 4; ++df){
#pragma unroll
    for (int h = 0; h < 2; ++h){
      u32 w = pack2bf(oacc[df][2 * h] * inv, oacc[df][2 * h + 1] * inv);
      *(u32*)(orow + df * 16 + g * 4 + 2 * h) = w;
    }
  }
}

// ---------------- residual + layernorm (block per row of 1024) ----------------
__global__ __launch_bounds__(256) void ln_k(const float* res, const float* __restrict__ x,
                                            const float* __restrict__ g, const float* __restrict__ bta,
                                            float* hout, u16* __restrict__ hbf)
{
  int row = blockIdx.x, tid = threadIdx.x;
  const float* rr = res + ((size_t)row << 10);
  const float* xr = x + ((size_t)row << 10);
  float v[4]; float s = 0.0f, s2 = 0.0f;
#pragma unroll
  for (int k = 0; k < 4; ++k){
    int d = tid + (k << 8);
    float t = rr[d] + xr[d];
    v[k] = t; s += t; s2 += t * t;
  }
#pragma unroll
  for (int off = 32; off; off >>= 1){ s += __shfl_xor(s, off); s2 += __shfl_xor(s2, off); }
  __shared__ float ps[8];
  int wid = tid >> 6, lane = tid & 63;
  if (lane == 0){ ps[wid] = s; ps[wid + 4] = s2; }
  __syncthreads();
  s  = ps[0] + ps[1] + ps[2] + ps[3];
  s2 = ps[4] + ps[5] + ps[6] + ps[7];
  float mu = s * 0.0009765625f;
  float var = s2 * 0.0009765625f - mu * mu;
  float rstd = rsqrtf(var + 1e-5f);
  float* ho = hout + ((size_t)row << 10);
  u16* hb = hbf + ((size_t)row << 10);
#pragma unroll
  for (int k = 0; k < 4; ++k){
    int d = tid + (k << 8);
    float t = (v[k] - mu) * rstd * g[d] + bta[d];
    ho[d] = t; hb[d] = f2bf(t);
  }
}

__global__ __launch_bounds__(256) void copy_f32(const f32x4* __restrict__ src, f32x4* __restrict__ dst){
  size_t i = (size_t)blockIdx.x * 256 + threadIdx.x;
  dst[i] = src[i];
}

extern "C" void kernel_launch(void* const* d_in, const int* in_sizes, int n_in,
                              void* d_out, int out_size, void* d_ws, size_t ws_size,
                              hipStream_t stream)
{
  const int*   data = (const int*)  d_in[0];
  const float* mems = (const float*)d_in[1];
  const float* emb  = (const float*)d_in[2];
  const float* Wq   = (const float*)d_in[3];
  const float* Wkv  = (const float*)d_in[4];
  const float* Wo   = (const float*)d_in[5];
  const float* ln1g = (const float*)d_in[6];
  const float* ln1b = (const float*)d_in[7];
  const float* W1   = (const float*)d_in[8];
  const float* b1   = (const float*)d_in[9];
  const float* W2   = (const float*)d_in[10];
  const float* b2   = (const float*)d_in[11];
  const float* ln2g = (const float*)d_in[12];
  const float* ln2b = (const float*)d_in[13];
  float* out = (float*)d_out;

  char* ws = (char*)d_ws;
  size_t off = 0;
  auto alloc = [&](size_t bytes) -> char* {
    char* p = ws + off;
    off = (off + bytes + 255) & ~(size_t)255;
    return p;
  };

  // transposed bf16 weights: [N][K] per layer
  u16*   wq_bf  = (u16*)  alloc((size_t)6 * 1024 * 1024 * 2);
  u16*   wkv_bf = (u16*)  alloc((size_t)6 * 1024 * 2048 * 2);
  u16*   wo_bf  = (u16*)  alloc((size_t)6 * 1024 * 1024 * 2);
  u16*   w1_bf  = (u16*)  alloc((size_t)6 * 1024 * 4096 * 2);
  u16*   w2_bf  = (u16*)  alloc((size_t)6 * 4096 * 1024 * 2);
  float* h      = (float*)alloc((size_t)2048 * 1024 * 4);
  u16*   hbf    = (u16*)  alloc((size_t)2048 * 1024 * 2);
  u16*   cbf    = (u16*)  alloc((size_t)4096 * 1024 * 2);
  u16*   qbf    = (u16*)  alloc((size_t)2048 * 1024 * 2);
  u16*   kvbf   = (u16*)  alloc((size_t)4096 * 2048 * 2);
  u16*   vtbf   = (u16*)  alloc((size_t)64 * 64 * 1024 * 2);
  u16*   attnbf = (u16*)  alloc((size_t)2048 * 1024 * 2);
  float* of_    = (float*)alloc((size_t)2048 * 1024 * 4);
  u16*   f1bf   = (u16*)  alloc((size_t)2048 * 4096 * 2);
  float* f2f    = (float*)alloc((size_t)2048 * 1024 * 4);

  // weights -> bf16 transposed (once per call; deterministic)
  conv_bf16_t<<<dim3(16, 16, 6), 256, 0, stream>>>(Wq,  wq_bf,  1024, 1024);
  conv_bf16_t<<<dim3(32, 16, 6), 256, 0, stream>>>(Wkv, wkv_bf, 1024, 2048);
  conv_bf16_t<<<dim3(16, 16, 6), 256, 0, stream>>>(Wo,  wo_bf,  1024, 1024);
  conv_bf16_t<<<dim3(64, 16, 6), 256, 0, stream>>>(W1,  w1_bf,  1024, 4096);
  conv_bf16_t<<<dim3(16, 64, 6), 256, 0, stream>>>(W2,  w2_bf,  4096, 1024);
  embed_k<<<8192, 256, 0, stream>>>(data, emb, h, hbf);

  for (int l = 0; l < 6; ++l){
    build_c_k<<<16384, 256, 0, stream>>>(mems + (size_t)l * 2048 * 1024, hbf, cbf);
    gemm_bt<64><<<dim3(8, 32),   256, 0, stream>>>(hbf, wq_bf  + (size_t)l * 1024 * 1024, nullptr, nullptr, qbf, 2048, 1024, 1024, 0);
    gemm_bt<128><<<dim3(16, 32), 256, 0, stream>>>(cbf, wkv_bf + (size_t)l * 1024 * 2048, nullptr, nullptr, kvbf, 4096, 2048, 1024, 0);
    vtrans<<<dim3(16, 64), 256, 0, stream>>>(kvbf, vtbf);
    attn_mfma<<<dim3(8, 64), 256, 0, stream>>>(qbf, kvbf, vtbf, attnbf);
    gemm_bt<64><<<dim3(8, 32),   256, 0, stream>>>(attnbf, wo_bf + (size_t)l * 1024 * 1024, nullptr, of_, nullptr, 2048, 1024, 1024, 0);
    ln_k<<<2048, 256, 0, stream>>>(h, of_, ln1g + l * 1024, ln1b + l * 1024, h, hbf);
    gemm_bt<128><<<dim3(32, 16), 256, 0, stream>>>(hbf,  w1_bf + (size_t)l * 1024 * 4096, b1 + (size_t)l * 4096, nullptr, f1bf, 2048, 4096, 1024, 1);
    gemm_bt<64><<<dim3(8, 32),   256, 0, stream>>>(f1bf, w2_bf + (size_t)l * 4096 * 1024, b2 + (size_t)l * 1024, f2f, nullptr, 2048, 1024, 4096, 0);
    ln_k<<<2048, 256, 0, stream>>>(h, f2f, ln2g + l * 1024, ln2b + l * 1024, h, hbf);
  }
  copy_f32<<<2048, 256, 0, stream>>>((const f32x4*)h, (f32x4*)out);
}

// Round 4
// 1586.542 us; speedup vs baseline: 15.3820x; 1.1717x over previous
//
#include <hip/hip_runtime.h>

typedef unsigned short u16;
typedef unsigned int u32;
typedef __bf16 bf16x8 __attribute__((ext_vector_type(8)));
typedef float f32x4 __attribute__((ext_vector_type(4)));
typedef u16 u16x8 __attribute__((ext_vector_type(8)));
typedef u16 u16x4 __attribute__((ext_vector_type(4)));
typedef u32 u32x4 __attribute__((ext_vector_type(4)));

__device__ __forceinline__ u16 f2bf(float f){
  unsigned u = __float_as_uint(f);
  u += 0x7FFFu + ((u >> 16) & 1u);   // RNE
  return (u16)(u >> 16);
}
__device__ __forceinline__ u32 pack2bf(float a, float b){
  return (u32)f2bf(a) | ((u32)f2bf(b) << 16);
}
__device__ __forceinline__ void gload16(const void* g, void* l){
  __builtin_amdgcn_global_load_lds(
      (const __attribute__((address_space(1))) void*)g,
      (__attribute__((address_space(3))) void*)l, 16, 0, 0);
}

// ---------------- weight f32 [K][N] -> bf16 [N][K] (transposing convert) ----------------
__global__ __launch_bounds__(256) void conv_bf16_t(const float* __restrict__ src, u16* __restrict__ dst,
                                                   int K, int N){
  __shared__ u16 s[64 * 68];
  size_t lo = (size_t)blockIdx.z * K * N;
  int n0 = blockIdx.x << 6, k0 = blockIdx.y << 6;
  int t = threadIdx.x;
#pragma unroll
  for (int p = 0; p < 16; ++p){
    int idx = p * 256 + t;
    int kl = idx >> 6, nl = idx & 63;
    s[nl * 68 + kl] = f2bf(src[lo + (size_t)(k0 + kl) * N + n0 + nl]);
  }
  __syncthreads();
#pragma unroll
  for (int p = 0; p < 16; ++p){
    int idx = p * 256 + t;
    int nl = idx >> 6, kl = idx & 63;
    dst[lo + (size_t)(n0 + nl) * K + k0 + kl] = s[nl * 68 + kl];
  }
}

// ---------------- embedding + positional encoding ----------------
__global__ __launch_bounds__(256) void embed_k(const int* __restrict__ data, const float* __restrict__ emb,
                                               float* __restrict__ h, u16* __restrict__ hbf){
  int idx = blockIdx.x * 256 + threadIdx.x;       // 0 .. 2M-1
  int r = idx >> 10, d = idx & 1023;              // r = i*4+b
  int i = r >> 2;
  int e = data[r];
  float val = emb[(size_t)e * 1024 + d] * 32.0f;  // sqrt(1024)
  float pos = (float)(511 - i);
  int t = d & 511;
  float freq = powf(10000.0f, -(float)t * (1.0f / 512.0f));
  float ang = pos * freq;
  val += (d < 512) ? sinf(ang) : cosf(ang);
  h[idx] = val;
  hbf[idx] = f2bf(val);
}

// ---------------- build concat(mems[l], h) in bf16 ----------------
__global__ __launch_bounds__(256) void build_c_k(const float* __restrict__ memsl, const u16* __restrict__ hbf,
                                                 u16* __restrict__ cbf){
  int idx = blockIdx.x * 256 + threadIdx.x;       // 0 .. 4M-1
  u16 v;
  if (idx < 2097152) v = f2bf(memsl[idx]);
  else               v = hbf[idx - 2097152];
  cbf[idx] = v;
}

// ---------------- bf16 MFMA GEMM: C = A[M,K] @ Bt[N,K]^T, optional split-K ----------------
// blockIdx.z = K-chunk; kchunk = K/gridDim.z. If Cpart: write f32 partial (no bias).
template<int BM>
__global__ __launch_bounds__(256) void gemm_bt(
    const u16* __restrict__ A, const u16* __restrict__ Bt,
    const float* __restrict__ bias, float* __restrict__ C, u16* __restrict__ Cbf,
    float* __restrict__ Cpart, int M, int N, int K, int kchunk, int relu)
{
  constexpr int MFR = BM / 32;            // A frags per wave
  __shared__ __align__(16) u16 sA[BM * 32];
  __shared__ __align__(16) u16 sB[128 * 32];
  int tid = threadIdx.x, lane = tid & 63;
  int wr = (tid >> 7) & 1, wc = (tid >> 6) & 1;   // 2x2 wave grid
  int m0 = blockIdx.y * BM, n0 = blockIdx.x << 7;
  int kbeg = blockIdx.z * kchunk;

  f32x4 acc[MFR][4];
#pragma unroll
  for (int i = 0; i < MFR; ++i)
#pragma unroll
    for (int j = 0; j < 4; ++j) acc[i][j] = (f32x4)(0.0f);

  int srow = tid >> 2;                    // 0..63
  int scol = (tid & 3) << 3;              // k-element offset 0,8,16,24
  const u16* Ab = A + (size_t)(m0 + srow) * K + kbeg + scol;
  const u16* Bb = Bt + (size_t)(n0 + srow) * K + kbeg + scol;
  const size_t rstep = (size_t)K << 6;    // 64 rows

  const u16* pa = sA + (wr * (BM / 2) + (lane & 15)) * 32 + ((lane >> 4) << 3);
  const u16* pb = sB + (wc * 64 + (lane & 15)) * 32 + ((lane >> 4) << 3);

  for (int k0 = 0; k0 < kchunk; k0 += 32){
#pragma unroll
    for (int c = 0; c < BM / 64; ++c)
      gload16(Ab + c * rstep + k0, (void*)&sA[c * 2048 + tid * 8]);
#pragma unroll
    for (int c = 0; c < 2; ++c)
      gload16(Bb + c * rstep + k0, (void*)&sB[c * 2048 + tid * 8]);
    __syncthreads();

    bf16x8 af[MFR], bfv[4];
#pragma unroll
    for (int mi = 0; mi < MFR; ++mi) af[mi] = *(const bf16x8*)(pa + mi * 16 * 32);
#pragma unroll
    for (int ni = 0; ni < 4; ++ni)   bfv[ni] = *(const bf16x8*)(pb + ni * 16 * 32);
#pragma unroll
    for (int mi = 0; mi < MFR; ++mi)
#pragma unroll
      for (int ni = 0; ni < 4; ++ni)
        acc[mi][ni] = __builtin_amdgcn_mfma_f32_16x16x32_bf16(af[mi], bfv[ni], acc[mi][ni], 0, 0, 0);
    __syncthreads();
  }

  int colf = lane & 15, rowf = (lane >> 4) << 2;
  if (Cpart){
    float* dst = Cpart + (size_t)blockIdx.z * M * N;
#pragma unroll
    for (int ni = 0; ni < 4; ++ni){
      int cg = n0 + (wc << 6) + ni * 16 + colf;
#pragma unroll
      for (int mi = 0; mi < MFR; ++mi){
        int rg = m0 + wr * (BM / 2) + mi * 16 + rowf;
#pragma unroll
        for (int r = 0; r < 4; ++r)
          dst[(size_t)(rg + r) * N + cg] = acc[mi][ni][r];
      }
    }
  } else {
#pragma unroll
    for (int ni = 0; ni < 4; ++ni){
      int cg = n0 + (wc << 6) + ni * 16 + colf;
      float bv = bias ? bias[cg] : 0.0f;
#pragma unroll
      for (int mi = 0; mi < MFR; ++mi){
        int rg = m0 + wr * (BM / 2) + mi * 16 + rowf;
#pragma unroll
        for (int r = 0; r < 4; ++r){
          float val = acc[mi][ni][r] + bv;
          if (relu) val = fmaxf(val, 0.0f);
          size_t o = (size_t)(rg + r) * N + cg;
          if (C)   C[o]   = val;
          if (Cbf) Cbf[o] = f2bf(val);
        }
      }
    }
  }
}

// ---------------- split-K partial sum -> bf16 ----------------
__global__ __launch_bounds__(256) void reduce_bf16(const float* __restrict__ parts, size_t pstride,
                                                   int np, u16* __restrict__ dst){
  size_t i = ((size_t)blockIdx.x * 256 + threadIdx.x) * 4;
  f32x4 s = *(const f32x4*)(parts + i);
  for (int p = 1; p < np; ++p){
    f32x4 v = *(const f32x4*)(parts + p * pstride + i);
#pragma unroll
    for (int j = 0; j < 4; ++j) s[j] += v[j];
  }
  u16x4 o;
#pragma unroll
  for (int j = 0; j < 4; ++j) o[j] = f2bf(s[j]);
  *(u16x4*)(dst + i) = o;
}

// ---------------- V transpose: kvbf [(j*4+b)][n*128+64+d] -> vtbf [bn][d][j] ----------------
__global__ __launch_bounds__(256) void vtrans(const u16* __restrict__ kvbf, u16* __restrict__ vtbf){
  __shared__ u16 s[64 * 68];
  int jt = blockIdx.x, bnp = blockIdx.y;
  int b = bnp >> 4, n = bnp & 15;
  int t = threadIdx.x;
  int j0 = jt << 6;
#pragma unroll
  for (int rr = 0; rr < 16; ++rr){
    int idx = rr * 256 + t;
    int jl = idx >> 6, dd = idx & 63;
    s[jl * 68 + dd] = kvbf[((size_t)((j0 + jl) * 4 + b) << 11) + n * 128 + 64 + dd];
  }
  __syncthreads();
#pragma unroll
  for (int ww = 0; ww < 16; ++ww){
    int idx = ww * 256 + t;
    int dd = idx >> 6, jl = idx & 63;
    vtbf[((size_t)(bnp * 64 + dd) << 10) + j0 + jl] = s[jl * 68 + dd];
  }
}

// ---------------- MFMA flash attention (unchanged, verified) ----------------
__global__ __launch_bounds__(256) void attn_mfma(
    const u16* __restrict__ qbf, const u16* __restrict__ kvbf,
    const u16* __restrict__ vtbf, u16* __restrict__ attnbf)
{
  int tid = threadIdx.x, lane = tid & 63, wid = tid >> 6;
  int g = lane >> 4, t = lane & 15;
  int qt = blockIdx.x, bnp = blockIdx.y;
  int b = bnp >> 4, n = bnp & 15;
  int i0 = qt * 64 + wid * 16;
  int i = i0 + t;

  union Cvt { u32x4 u; bf16x8 v; };

  bf16x8 qfrag[2];
#pragma unroll
  for (int ks = 0; ks < 2; ++ks)
    qfrag[ks] = *(const bf16x8*)(qbf + ((size_t)(i * 4 + b) << 10) + n * 64 + ks * 32 + g * 8);

  f32x4 oacc[4];
#pragma unroll
  for (int df = 0; df < 4; ++df) oacc[df] = (f32x4)(0.0f);
  float mrun = -1e30f, lrun = 0.0f;

  int nt = ((i0 + 527) >> 6) + 1;
  for (int kt = 0; kt < nt; ++kt){
    int j0 = kt << 6;
    f32x4 sacc[4];
#pragma unroll
    for (int jf = 0; jf < 4; ++jf) sacc[jf] = (f32x4)(0.0f);
#pragma unroll
    for (int ks = 0; ks < 2; ++ks){
#pragma unroll
      for (int jf = 0; jf < 4; ++jf){
        int j = j0 + jf * 16 + t;
        bf16x8 kf = *(const bf16x8*)(kvbf + ((size_t)(j * 4 + b) << 11) + n * 128 + ks * 32 + g * 8);
        sacc[jf] = __builtin_amdgcn_mfma_f32_16x16x32_bf16(kf, qfrag[ks], sacc[jf], 0, 0, 0);
      }
    }
    bool part = (j0 + 63 > i0 + 512);
    float ps[4][4];
    float tmax = -1e30f;
#pragma unroll
    for (int jf = 0; jf < 4; ++jf)
#pragma unroll
      for (int r = 0; r < 4; ++r){
        float s = sacc[jf][r] * 0.125f;
        if (part && (j0 + jf * 16 + g * 4 + r > i + 512)) s = -1e30f;
        ps[jf][r] = s;
        tmax = fmaxf(tmax, s);
      }
    tmax = fmaxf(tmax, __shfl_xor(tmax, 16));
    tmax = fmaxf(tmax, __shfl_xor(tmax, 32));
    float mnew = fmaxf(mrun, tmax);
    float sc = __expf(mrun - mnew);
    mrun = mnew;
    lrun *= sc;
    u32 pk0[2], pk1[2], pk2[2], pk3[2];
    {
      float e0, e1, e2, e3;
#define DO_JF(PK, JF) \
      e0 = __expf(ps[JF][0] - mnew); e1 = __expf(ps[JF][1] - mnew); \
      e2 = __expf(ps[JF][2] - mnew); e3 = __expf(ps[JF][3] - mnew); \
      lrun += (e0 + e1) + (e2 + e3); \
      PK[0] = pack2bf(e0, e1); PK[1] = pack2bf(e2, e3);
      DO_JF(pk0, 0) DO_JF(pk1, 1) DO_JF(pk2, 2) DO_JF(pk3, 3)
#undef DO_JF
    }
#pragma unroll
    for (int df = 0; df < 4; ++df)
#pragma unroll
      for (int r = 0; r < 4; ++r) oacc[df][r] *= sc;

    int srcA = t + 16 * ((2 * g) & 3);
    int srcB = t + 16 * ((2 * g + 1) & 3);
    bool ghi = (g >= 2);
#pragma unroll
    for (int ks = 0; ks < 2; ++ks){
      u32 w0a, w1a, w2a, w3a, w0b, w1b, w2b, w3b;
      if (ks == 0){
        w0a = __shfl((int)pk0[0], srcA); w1a = __shfl((int)pk0[1], srcA);
        w2a = __shfl((int)pk0[0], srcB); w3a = __shfl((int)pk0[1], srcB);
        w0b = __shfl((int)pk1[0], srcA); w1b = __shfl((int)pk1[1], srcA);
        w2b = __shfl((int)pk1[0], srcB); w3b = __shfl((int)pk1[1], srcB);
      } else {
        w0a = __shfl((int)pk2[0], srcA); w1a = __shfl((int)pk2[1], srcA);
        w2a = __shfl((int)pk2[0], srcB); w3a = __shfl((int)pk2[1], srcB);
        w0b = __shfl((int)pk3[0], srcA); w1b = __shfl((int)pk3[1], srcA);
        w2b = __shfl((int)pk3[0], srcB); w3b = __shfl((int)pk3[1], srcB);
      }
      Cvt c;
      c.u[0] = ghi ? w0b : w0a;
      c.u[1] = ghi ? w1b : w1a;
      c.u[2] = ghi ? w2b : w2a;
      c.u[3] = ghi ? w3b : w3a;
      bf16x8 pf = c.v;
#pragma unroll
      for (int df = 0; df < 4; ++df){
        bf16x8 vf = *(const bf16x8*)(vtbf + ((size_t)(bnp * 64 + df * 16 + t) << 10) + j0 + ks * 32 + g * 8);
        oacc[df] = __builtin_amdgcn_mfma_f32_16x16x32_bf16(vf, pf, oacc[df], 0, 0, 0);
      }
    }
  }
  lrun += __shfl_xor(lrun, 16);
  lrun += __shfl_xor(lrun, 32);
  float inv = 1.0f / lrun;

  u16* orow = attnbf + ((size_t)(i * 4 + b) << 10) + n * 64;
#pragma unroll
  for (int df = 0; df < 4; ++df){
#pragma unroll
    for (int h = 0; h < 2; ++h){
      u32 w = pack2bf(oacc[df][2 * h] * inv, oacc[df][2 * h + 1] * inv);
      *(u32*)(orow + df * 16 + g * 4 + 2 * h) = w;
    }
  }
}

// ---------------- residual + (split-K partial sum) + bias + layernorm ----------------
__global__ __launch_bounds__(256) void ln_k(const float* __restrict__ res, const float* __restrict__ parts,
                                            size_t pstride, int np, const float* __restrict__ bias,
                                            const float* __restrict__ g, const float* __restrict__ bta,
                                            float* hout, u16* __restrict__ hbf)
{
  int row = blockIdx.x, tid = threadIdx.x;
  const float* rr = res + ((size_t)row << 10);
  float v[4]; float s = 0.0f, s2 = 0.0f;
#pragma unroll
  for (int k = 0; k < 4; ++k){
    int d = tid + (k << 8);
    float t = rr[d] + (bias ? bias[d] : 0.0f);
    for (int p = 0; p < np; ++p) t += parts[p * pstride + ((size_t)row << 10) + d];
    v[k] = t; s += t; s2 += t * t;
  }
#pragma unroll
  for (int off = 32; off; off >>= 1){ s += __shfl_xor(s, off); s2 += __shfl_xor(s2, off); }
  __shared__ float ps[8];
  int wid = tid >> 6, lane = tid & 63;
  if (lane == 0){ ps[wid] = s; ps[wid + 4] = s2; }
  __syncthreads();
  s  = ps[0] + ps[1] + ps[2] + ps[3];
  s2 = ps[4] + ps[5] + ps[6] + ps[7];
  float mu = s * 0.0009765625f;
  float var = s2 * 0.0009765625f - mu * mu;
  float rstd = rsqrtf(var + 1e-5f);
  float* ho = hout + ((size_t)row << 10);
  u16* hb = hbf + ((size_t)row << 10);
#pragma unroll
  for (int k = 0; k < 4; ++k){
    int d = tid + (k << 8);
    float t = (v[k] - mu) * rstd * g[d] + bta[d];
    ho[d] = t; hb[d] = f2bf(t);
  }
}

__global__ __launch_bounds__(256) void copy_f32(const f32x4* __restrict__ src, f32x4* __restrict__ dst){
  size_t i = (size_t)blockIdx.x * 256 + threadIdx.x;
  dst[i] = src[i];
}

extern "C" void kernel_launch(void* const* d_in, const int* in_sizes, int n_in,
                              void* d_out, int out_size, void* d_ws, size_t ws_size,
                              hipStream_t stream)
{
  const int*   data = (const int*)  d_in[0];
  const float* mems = (const float*)d_in[1];
  const float* emb  = (const float*)d_in[2];
  const float* Wq   = (const float*)d_in[3];
  const float* Wkv  = (const float*)d_in[4];
  const float* Wo   = (const float*)d_in[5];
  const float* ln1g = (const float*)d_in[6];
  const float* ln1b = (const float*)d_in[7];
  const float* W1   = (const float*)d_in[8];
  const float* b1   = (const float*)d_in[9];
  const float* W2   = (const float*)d_in[10];
  const float* b2   = (const float*)d_in[11];
  const float* ln2g = (const float*)d_in[12];
  const float* ln2b = (const float*)d_in[13];
  float* out = (float*)d_out;

  char* ws = (char*)d_ws;
  size_t off = 0;
  auto alloc = [&](size_t bytes) -> char* {
    char* p = ws + off;
    off = (off + bytes + 255) & ~(size_t)255;
    return p;
  };

  // transposed bf16 weights: [N][K] per layer
  u16*   wq_bf  = (u16*)  alloc((size_t)6 * 1024 * 1024 * 2);
  u16*   wkv_bf = (u16*)  alloc((size_t)6 * 1024 * 2048 * 2);
  u16*   wo_bf  = (u16*)  alloc((size_t)6 * 1024 * 1024 * 2);
  u16*   w1_bf  = (u16*)  alloc((size_t)6 * 1024 * 4096 * 2);
  u16*   w2_bf  = (u16*)  alloc((size_t)6 * 4096 * 1024 * 2);
  float* h      = (float*)alloc((size_t)2048 * 1024 * 4);
  u16*   hbf    = (u16*)  alloc((size_t)2048 * 1024 * 2);
  u16*   cbf    = (u16*)  alloc((size_t)4096 * 1024 * 2);
  u16*   qbf    = (u16*)  alloc((size_t)2048 * 1024 * 2);
  u16*   kvbf   = (u16*)  alloc((size_t)4096 * 2048 * 2);
  u16*   vtbf   = (u16*)  alloc((size_t)64 * 64 * 1024 * 2);
  u16*   attnbf = (u16*)  alloc((size_t)2048 * 1024 * 2);
  u16*   f1bf   = (u16*)  alloc((size_t)2048 * 4096 * 2);
  float* pbuf   = (float*)alloc((size_t)4 * 2048 * 1024 * 4);   // split-K partials (reused)
  const size_t PS = (size_t)2048 * 1024;

  // weights -> bf16 transposed (once per call; deterministic)
  conv_bf16_t<<<dim3(16, 16, 6), 256, 0, stream>>>(Wq,  wq_bf,  1024, 1024);
  conv_bf16_t<<<dim3(32, 16, 6), 256, 0, stream>>>(Wkv, wkv_bf, 1024, 2048);
  conv_bf16_t<<<dim3(16, 16, 6), 256, 0, stream>>>(Wo,  wo_bf,  1024, 1024);
  conv_bf16_t<<<dim3(64, 16, 6), 256, 0, stream>>>(W1,  w1_bf,  1024, 4096);
  conv_bf16_t<<<dim3(16, 64, 6), 256, 0, stream>>>(W2,  w2_bf,  4096, 1024);
  embed_k<<<8192, 256, 0, stream>>>(data, emb, h, hbf);

  for (int l = 0; l < 6; ++l){
    build_c_k<<<16384, 256, 0, stream>>>(mems + (size_t)l * 2048 * 1024, hbf, cbf);
    // Wq: split-K x2 -> partials -> qbf
    gemm_bt<64><<<dim3(8, 32, 2),  256, 0, stream>>>(hbf, wq_bf  + (size_t)l * 1024 * 1024, nullptr, nullptr, nullptr, pbuf, 2048, 1024, 1024, 512, 0);
    reduce_bf16<<<2048, 256, 0, stream>>>(pbuf, PS, 2, qbf);
    // Wkv: 1024 blocks, direct
    gemm_bt<64><<<dim3(16, 64),    256, 0, stream>>>(cbf, wkv_bf + (size_t)l * 1024 * 2048, nullptr, nullptr, kvbf, nullptr, 4096, 2048, 1024, 1024, 0);
    vtrans<<<dim3(16, 64), 256, 0, stream>>>(kvbf, vtbf);
    attn_mfma<<<dim3(8, 64), 256, 0, stream>>>(qbf, kvbf, vtbf, attnbf);
    // Wo: split-K x2 -> partials, summed inside ln1
    gemm_bt<64><<<dim3(8, 32, 2),  256, 0, stream>>>(attnbf, wo_bf + (size_t)l * 1024 * 1024, nullptr, nullptr, nullptr, pbuf, 2048, 1024, 1024, 512, 0);
    ln_k<<<2048, 256, 0, stream>>>(h, pbuf, PS, 2, nullptr, ln1g + l * 1024, ln1b + l * 1024, h, hbf);
    // W1: 1024 blocks, direct + bias + relu
    gemm_bt<64><<<dim3(32, 32),    256, 0, stream>>>(hbf,  w1_bf + (size_t)l * 1024 * 4096, b1 + (size_t)l * 4096, nullptr, f1bf, nullptr, 2048, 4096, 1024, 1024, 1);
    // W2: split-K x4 -> partials, summed (+b2) inside ln2
    gemm_bt<64><<<dim3(8, 32, 4),  256, 0, stream>>>(f1bf, w2_bf + (size_t)l * 4096 * 1024, nullptr, nullptr, nullptr, pbuf, 2048, 1024, 4096, 1024, 0);
    ln_k<<<2048, 256, 0, stream>>>(h, pbuf, PS, 4, b2 + (size_t)l * 1024, ln2g + l * 1024, ln2b + l * 1024, h, hbf);
  }
  copy_f32<<<2048, 256, 0, stream>>>((const f32x4*)h, (f32x4*)out);
}

// Round 5
// 1516.057 us; speedup vs baseline: 16.0971x; 1.0465x over previous
//
#include <hip/hip_runtime.h>

typedef unsigned short u16;
typedef unsigned int u32;
typedef __bf16 bf16x8 __attribute__((ext_vector_type(8)));
typedef float f32x4 __attribute__((ext_vector_type(4)));
typedef u16 u16x8 __attribute__((ext_vector_type(8)));
typedef u16 u16x4 __attribute__((ext_vector_type(4)));
typedef u32 u32x4 __attribute__((ext_vector_type(4)));

__device__ __forceinline__ u16 f2bf(float f){
  unsigned u = __float_as_uint(f);
  u += 0x7FFFu + ((u >> 16) & 1u);   // RNE
  return (u16)(u >> 16);
}
__device__ __forceinline__ u32 pack2bf(float a, float b){
  return (u32)f2bf(a) | ((u32)f2bf(b) << 16);
}
__device__ __forceinline__ void gload16(const void* g, void* l){
  __builtin_amdgcn_global_load_lds(
      (const __attribute__((address_space(1))) void*)g,
      (__attribute__((address_space(3))) void*)l, 16, 0, 0);
}

// ---------------- weight f32 [K][N] -> bf16 [drow0+N][K] (transposing convert) ----------------
__global__ __launch_bounds__(256) void conv_bf16_t(const float* __restrict__ src, u16* __restrict__ dst,
                                                   int K, int N, size_t dls, int drow0){
  __shared__ u16 s[64 * 68];
  size_t lo = (size_t)blockIdx.z * K * N;
  int n0 = blockIdx.x << 6, k0 = blockIdx.y << 6;
  int t = threadIdx.x;
#pragma unroll
  for (int p = 0; p < 4; ++p){
    int idx = p * 1024 + t * 4;
    int kl = idx >> 6, nl = idx & 63;
    f32x4 v = *(const f32x4*)(src + lo + (size_t)(k0 + kl) * N + n0 + nl);
#pragma unroll
    for (int j = 0; j < 4; ++j) s[(nl + j) * 68 + kl] = f2bf(v[j]);
  }
  __syncthreads();
  u16* db = dst + blockIdx.z * dls;
#pragma unroll
  for (int p = 0; p < 4; ++p){
    int idx = p * 1024 + t * 4;
    int nl = idx >> 6, kl = idx & 63;
    u16x4 o;
#pragma unroll
    for (int j = 0; j < 4; ++j) o[j] = s[nl * 68 + kl + j];
    *(u16x4*)(db + (size_t)(drow0 + n0 + nl) * K + k0 + kl) = o;
  }
}

// ---------------- plain f32 -> bf16 ----------------
__global__ __launch_bounds__(256) void conv_bf16(const float* __restrict__ src, u16* __restrict__ dst){
  size_t i = ((size_t)blockIdx.x * 256 + threadIdx.x) * 4;
  f32x4 v = *(const f32x4*)(src + i);
  u16x4 o;
#pragma unroll
  for (int j = 0; j < 4; ++j) o[j] = f2bf(v[j]);
  *(u16x4*)(dst + i) = o;
}

// ---------------- embedding + positional encoding ----------------
__global__ __launch_bounds__(256) void embed_k(const int* __restrict__ data, const float* __restrict__ emb,
                                               float* __restrict__ h, u16* __restrict__ hbf){
  int idx = blockIdx.x * 256 + threadIdx.x;       // 0 .. 2M-1
  int r = idx >> 10, d = idx & 1023;              // r = i*4+b
  int i = r >> 2;
  int e = data[r];
  float val = emb[(size_t)e * 1024 + d] * 32.0f;  // sqrt(1024)
  float pos = (float)(511 - i);
  int t = d & 511;
  float freq = powf(10000.0f, -(float)t * (1.0f / 512.0f));
  float ang = pos * freq;
  val += (d < 512) ? sinf(ang) : cosf(ang);
  h[idx] = val;
  hbf[idx] = f2bf(val);
}

// ---------------- bf16 MFMA GEMM: C = A[M,K] @ Bt[N,K]^T ----------------
// 2-phase double-buffered LDS; blockIdx.z = K-chunk (if Cpart) or batch (zA/zB/zC strides).
template<int BM>
__global__ __launch_bounds__(256) void gemm_bt(
    const u16* __restrict__ A, const u16* __restrict__ Bt,
    const float* __restrict__ bias, float* __restrict__ C, u16* __restrict__ Cbf,
    float* __restrict__ Cpart, int M, int N, int K, int kchunk, int relu,
    size_t zA, size_t zB, size_t zC)
{
  constexpr int MFR = BM / 32;
  constexpr int ASZ = BM * 32, BSZ = 128 * 32;
  __shared__ __align__(16) u16 sA[2 * ASZ];
  __shared__ __align__(16) u16 sB[2 * BSZ];
  int tid = threadIdx.x, lane = tid & 63;
  int wr = (tid >> 7) & 1, wc = (tid >> 6) & 1;
  int m0 = blockIdx.y * BM, n0 = blockIdx.x << 7;
  int z = blockIdx.z;
  int kbeg = Cpart ? z * kchunk : 0;

  const u16* Ap = A + (size_t)z * zA;
  const u16* Bp = Bt + (size_t)z * zB;

  f32x4 acc[MFR][4];
#pragma unroll
  for (int i = 0; i < MFR; ++i)
#pragma unroll
    for (int j = 0; j < 4; ++j) acc[i][j] = (f32x4)(0.0f);

  int srow = tid >> 2;
  int scol = (tid & 3) << 3;
  const u16* Ab = Ap + (size_t)(m0 + srow) * K + kbeg + scol;
  const u16* Bb = Bp + (size_t)(n0 + srow) * K + kbeg + scol;
  const size_t rstep = (size_t)K << 6;    // 64 rows

  auto stage = [&](int buf, int k0){
#pragma unroll
    for (int c = 0; c < BM / 64; ++c)
      gload16(Ab + c * rstep + k0, (void*)&sA[buf * ASZ + c * 2048 + tid * 8]);
#pragma unroll
    for (int c = 0; c < 2; ++c)
      gload16(Bb + c * rstep + k0, (void*)&sB[buf * BSZ + c * 2048 + tid * 8]);
  };

  const int pa_off = (wr * (BM / 2) + (lane & 15)) * 32 + ((lane >> 4) << 3);
  const int pb_off = (wc * 64 + (lane & 15)) * 32 + ((lane >> 4) << 3);

  stage(0, 0);
  __syncthreads();
  int nk = kchunk >> 5;
  for (int t = 0; t < nk; ++t){
    int cur = t & 1;
    if (t + 1 < nk) stage(cur ^ 1, (t + 1) << 5);
    const u16* pa = sA + cur * ASZ + pa_off;
    const u16* pb = sB + cur * BSZ + pb_off;
    bf16x8 af[MFR], bfv[4];
#pragma unroll
    for (int mi = 0; mi < MFR; ++mi) af[mi] = *(const bf16x8*)(pa + mi * 16 * 32);
#pragma unroll
    for (int ni = 0; ni < 4; ++ni)   bfv[ni] = *(const bf16x8*)(pb + ni * 16 * 32);
#pragma unroll
    for (int mi = 0; mi < MFR; ++mi)
#pragma unroll
      for (int ni = 0; ni < 4; ++ni)
        acc[mi][ni] = __builtin_amdgcn_mfma_f32_16x16x32_bf16(af[mi], bfv[ni], acc[mi][ni], 0, 0, 0);
    __syncthreads();
  }

  int colf = lane & 15, rowf = (lane >> 4) << 2;
  if (Cpart){
    float* dst = Cpart + (size_t)z * M * N;
#pragma unroll
    for (int ni = 0; ni < 4; ++ni){
      int cg = n0 + (wc << 6) + ni * 16 + colf;
#pragma unroll
      for (int mi = 0; mi < MFR; ++mi){
        int rg = m0 + wr * (BM / 2) + mi * 16 + rowf;
#pragma unroll
        for (int r = 0; r < 4; ++r)
          dst[(size_t)(rg + r) * N + cg] = acc[mi][ni][r];
      }
    }
  } else {
#pragma unroll
    for (int ni = 0; ni < 4; ++ni){
      int cg = n0 + (wc << 6) + ni * 16 + colf;
      float bv = bias ? bias[cg] : 0.0f;
#pragma unroll
      for (int mi = 0; mi < MFR; ++mi){
        int rg = m0 + wr * (BM / 2) + mi * 16 + rowf;
#pragma unroll
        for (int r = 0; r < 4; ++r){
          float val = acc[mi][ni][r] + bv;
          if (relu) val = fmaxf(val, 0.0f);
          size_t o = (size_t)(rg + r) * N + cg;
          if (C)   C[o]   = val;
          if (Cbf) (Cbf + (size_t)z * zC)[o] = f2bf(val);
        }
      }
    }
  }
}

// ---------------- V transpose into vtbf [bn][d][jdst0 + j] ----------------
// src rows are (j_local*4+b) at stride sstride; V cols at co + n*128 + 64 + d.
__global__ __launch_bounds__(256) void vtrans(const u16* __restrict__ src, int sstride, int co,
                                              u16* __restrict__ dst, int jdst0,
                                              size_t zsrc, size_t zdst){
  __shared__ u16 s[64 * 68];
  int jt = blockIdx.x, bnp = blockIdx.y;
  int b = bnp >> 4, n = bnp & 15;
  int t = threadIdx.x;
  const u16* sp = src + blockIdx.z * zsrc;
  u16* dp = dst + blockIdx.z * zdst;
  int j0l = jt << 6;
#pragma unroll
  for (int rr = 0; rr < 16; ++rr){
    int idx = rr * 256 + t;
    int jl = idx >> 6, dd = idx & 63;
    s[jl * 68 + dd] = sp[(size_t)((j0l + jl) * 4 + b) * sstride + co + n * 128 + 64 + dd];
  }
  __syncthreads();
#pragma unroll
  for (int ww = 0; ww < 16; ++ww){
    int idx = ww * 256 + t;
    int dd = idx >> 6, jl = idx & 63;
    dp[((size_t)(bnp * 64 + dd) << 10) + jdst0 + j0l + jl] = s[jl * 68 + dd];
  }
}

// ---------------- MFMA flash attention (dual-source K: mems-KV + qkv) ----------------
__global__ __launch_bounds__(256) void attn_mfma(
    const u16* __restrict__ qkv, const u16* __restrict__ kvm,
    const u16* __restrict__ vtbf, u16* __restrict__ attnbf)
{
  int tid = threadIdx.x, lane = tid & 63, wid = tid >> 6;
  int g = lane >> 4, t = lane & 15;
  int qt = blockIdx.x, bnp = blockIdx.y;
  int b = bnp >> 4, n = bnp & 15;
  int i0 = qt * 64 + wid * 16;
  int i = i0 + t;

  union Cvt { u32x4 u; bf16x8 v; };

  bf16x8 qfrag[2];
#pragma unroll
  for (int ks = 0; ks < 2; ++ks)
    qfrag[ks] = *(const bf16x8*)(qkv + (size_t)(i * 4 + b) * 3072 + n * 64 + ks * 32 + g * 8);

  f32x4 oacc[4];
#pragma unroll
  for (int df = 0; df < 4; ++df) oacc[df] = (f32x4)(0.0f);
  float mrun = -1e30f, lrun = 0.0f;

  int nt = ((i0 + 527) >> 6) + 1;
  for (int kt = 0; kt < nt; ++kt){
    int j0 = kt << 6;
    const u16* kb; size_t kst; int joff;
    if (kt < 8){ kb = kvm + n * 128;        kst = 2048; joff = 0;   }
    else       { kb = qkv + 1024 + n * 128; kst = 3072; joff = 512; }
    f32x4 sacc[4];
#pragma unroll
    for (int jf = 0; jf < 4; ++jf) sacc[jf] = (f32x4)(0.0f);
#pragma unroll
    for (int ks = 0; ks < 2; ++ks){
#pragma unroll
      for (int jf = 0; jf < 4; ++jf){
        int j = j0 + jf * 16 + t - joff;
        bf16x8 kf = *(const bf16x8*)(kb + (size_t)(j * 4 + b) * kst + ks * 32 + g * 8);
        sacc[jf] = __builtin_amdgcn_mfma_f32_16x16x32_bf16(kf, qfrag[ks], sacc[jf], 0, 0, 0);
      }
    }
    bool part = (j0 + 63 > i0 + 512);
    float ps[4][4];
    float tmax = -1e30f;
#pragma unroll
    for (int jf = 0; jf < 4; ++jf)
#pragma unroll
      for (int r = 0; r < 4; ++r){
        float s = sacc[jf][r] * 0.125f;
        if (part && (j0 + jf * 16 + g * 4 + r > i + 512)) s = -1e30f;
        ps[jf][r] = s;
        tmax = fmaxf(tmax, s);
      }
    tmax = fmaxf(tmax, __shfl_xor(tmax, 16));
    tmax = fmaxf(tmax, __shfl_xor(tmax, 32));
    float mnew = fmaxf(mrun, tmax);
    float sc = __expf(mrun - mnew);
    mrun = mnew;
    lrun *= sc;
    u32 pk0[2], pk1[2], pk2[2], pk3[2];
    {
      float e0, e1, e2, e3;
#define DO_JF(PK, JF) \
      e0 = __expf(ps[JF][0] - mnew); e1 = __expf(ps[JF][1] - mnew); \
      e2 = __expf(ps[JF][2] - mnew); e3 = __expf(ps[JF][3] - mnew); \
      lrun += (e0 + e1) + (e2 + e3); \
      PK[0] = pack2bf(e0, e1); PK[1] = pack2bf(e2, e3);
      DO_JF(pk0, 0) DO_JF(pk1, 1) DO_JF(pk2, 2) DO_JF(pk3, 3)
#undef DO_JF
    }
#pragma unroll
    for (int df = 0; df < 4; ++df)
#pragma unroll
      for (int r = 0; r < 4; ++r) oacc[df][r] *= sc;

    int srcA = t + 16 * ((2 * g) & 3);
    int srcB = t + 16 * ((2 * g + 1) & 3);
    bool ghi = (g >= 2);
#pragma unroll
    for (int ks = 0; ks < 2; ++ks){
      u32 w0a, w1a, w2a, w3a, w0b, w1b, w2b, w3b;
      if (ks == 0){
        w0a = __shfl((int)pk0[0], srcA); w1a = __shfl((int)pk0[1], srcA);
        w2a = __shfl((int)pk0[0], srcB); w3a = __shfl((int)pk0[1], srcB);
        w0b = __shfl((int)pk1[0], srcA); w1b = __shfl((int)pk1[1], srcA);
        w2b = __shfl((int)pk1[0], srcB); w3b = __shfl((int)pk1[1], srcB);
      } else {
        w0a = __shfl((int)pk2[0], srcA); w1a = __shfl((int)pk2[1], srcA);
        w2a = __shfl((int)pk2[0], srcB); w3a = __shfl((int)pk2[1], srcB);
        w0b = __shfl((int)pk3[0], srcA); w1b = __shfl((int)pk3[1], srcA);
        w2b = __shfl((int)pk3[0], srcB); w3b = __shfl((int)pk3[1], srcB);
      }
      Cvt c;
      c.u[0] = ghi ? w0b : w0a;
      c.u[1] = ghi ? w1b : w1a;
      c.u[2] = ghi ? w2b : w2a;
      c.u[3] = ghi ? w3b : w3a;
      bf16x8 pf = c.v;
#pragma unroll
      for (int df = 0; df < 4; ++df){
        bf16x8 vf = *(const bf16x8*)(vtbf + ((size_t)(bnp * 64 + df * 16 + t) << 10) + j0 + ks * 32 + g * 8);
        oacc[df] = __builtin_amdgcn_mfma_f32_16x16x32_bf16(vf, pf, oacc[df], 0, 0, 0);
      }
    }
  }
  lrun += __shfl_xor(lrun, 16);
  lrun += __shfl_xor(lrun, 32);
  float inv = 1.0f / lrun;

  u16* orow = attnbf + ((size_t)(i * 4 + b) << 10) + n * 64;
#pragma unroll
  for (int df = 0; df < 4; ++df){
#pragma unroll
    for (int h = 0; h < 2; ++h){
      u32 w = pack2bf(oacc[df][2 * h] * inv, oacc[df][2 * h + 1] * inv);
      *(u32*)(orow + df * 16 + g * 4 + 2 * h) = w;
    }
  }
}

// ---------------- residual + (split-K partial sum) + bias + layernorm ----------------
__global__ __launch_bounds__(256) void ln_k(const float* __restrict__ res, const float* __restrict__ parts,
                                            size_t pstride, int np, const float* __restrict__ bias,
                                            const float* __restrict__ g, const float* __restrict__ bta,
                                            float* hout, u16* __restrict__ hbf)
{
  int row = blockIdx.x, tid = threadIdx.x;
  const float* rr = res + ((size_t)row << 10);
  float v[4]; float s = 0.0f, s2 = 0.0f;
#pragma unroll
  for (int k = 0; k < 4; ++k){
    int d = tid + (k << 8);
    float t = rr[d] + (bias ? bias[d] : 0.0f);
    for (int p = 0; p < np; ++p) t += parts[p * pstride + ((size_t)row << 10) + d];
    v[k] = t; s += t; s2 += t * t;
  }
#pragma unroll
  for (int off = 32; off; off >>= 1){ s += __shfl_xor(s, off); s2 += __shfl_xor(s2, off); }
  __shared__ float ps[8];
  int wid = tid >> 6, lane = tid & 63;
  if (lane == 0){ ps[wid] = s; ps[wid + 4] = s2; }
  __syncthreads();
  s  = ps[0] + ps[1] + ps[2] + ps[3];
  s2 = ps[4] + ps[5] + ps[6] + ps[7];
  float mu = s * 0.0009765625f;
  float var = s2 * 0.0009765625f - mu * mu;
  float rstd = rsqrtf(var + 1e-5f);
  float* ho = hout + ((size_t)row << 10);
  u16* hb = hbf + ((size_t)row << 10);
#pragma unroll
  for (int k = 0; k < 4; ++k){
    int d = tid + (k << 8);
    float t = (v[k] - mu) * rstd * g[d] + bta[d];
    ho[d] = t; hb[d] = f2bf(t);
  }
}

__global__ __launch_bounds__(256) void copy_f32(const f32x4* __restrict__ src, f32x4* __restrict__ dst){
  size_t i = (size_t)blockIdx.x * 256 + threadIdx.x;
  dst[i] = src[i];
}

extern "C" void kernel_launch(void* const* d_in, const int* in_sizes, int n_in,
                              void* d_out, int out_size, void* d_ws, size_t ws_size,
                              hipStream_t stream)
{
  const int*   data = (const int*)  d_in[0];
  const float* mems = (const float*)d_in[1];
  const float* emb  = (const float*)d_in[2];
  const float* Wq   = (const float*)d_in[3];
  const float* Wkv  = (const float*)d_in[4];
  const float* Wo   = (const float*)d_in[5];
  const float* ln1g = (const float*)d_in[6];
  const float* ln1b = (const float*)d_in[7];
  const float* W1   = (const float*)d_in[8];
  const float* b1   = (const float*)d_in[9];
  const float* W2   = (const float*)d_in[10];
  const float* b2   = (const float*)d_in[11];
  const float* ln2g = (const float*)d_in[12];
  const float* ln2b = (const float*)d_in[13];
  float* out = (float*)d_out;

  char* ws = (char*)d_ws;
  size_t off = 0;
  auto alloc = [&](size_t bytes) -> char* {
    char* p = ws + off;
    off = (off + bytes + 255) & ~(size_t)255;
    return p;
  };

  // fused transposed QKV weights: [l][3072][1024] (rows 0..1023 = Wq^T, 1024..3071 = Wkv^T)
  u16*   wqkv_bf = (u16*) alloc((size_t)6 * 3072 * 1024 * 2);
  u16*   wo_bf   = (u16*) alloc((size_t)6 * 1024 * 1024 * 2);
  u16*   w1_bf   = (u16*) alloc((size_t)6 * 4096 * 1024 * 2);
  u16*   w2_bf   = (u16*) alloc((size_t)6 * 1024 * 4096 * 2);
  u16*   memsbf  = (u16*) alloc((size_t)6 * 2048 * 1024 * 2);
  u16*   kvmem   = (u16*) alloc((size_t)6 * 2048 * 2048 * 2);   // per-layer mems-KV
  u16*   vtbf    = (u16*) alloc((size_t)6 * 64 * 64 * 1024 * 2);
  float* h       = (float*)alloc((size_t)2048 * 1024 * 4);
  u16*   hbf     = (u16*) alloc((size_t)2048 * 1024 * 2);
  u16*   qkv     = (u16*) alloc((size_t)2048 * 3072 * 2);
  u16*   attnbf  = (u16*) alloc((size_t)2048 * 1024 * 2);
  u16*   f1bf    = (u16*) alloc((size_t)2048 * 4096 * 2);
  float* pbuf    = (float*)alloc((size_t)4 * 2048 * 1024 * 4);
  const size_t PS = (size_t)2048 * 1024;
  const size_t VTL = (size_t)64 * 64 * 1024;

  // ---- layer-independent preamble (full-chip parallel) ----
  conv_bf16_t<<<dim3(16, 16, 6), 256, 0, stream>>>(Wq,  wqkv_bf, 1024, 1024, (size_t)3072 * 1024, 0);
  conv_bf16_t<<<dim3(32, 16, 6), 256, 0, stream>>>(Wkv, wqkv_bf, 1024, 2048, (size_t)3072 * 1024, 1024);
  conv_bf16_t<<<dim3(16, 16, 6), 256, 0, stream>>>(Wo,  wo_bf,   1024, 1024, (size_t)1024 * 1024, 0);
  conv_bf16_t<<<dim3(64, 16, 6), 256, 0, stream>>>(W1,  w1_bf,   1024, 4096, (size_t)4096 * 1024, 0);
  conv_bf16_t<<<dim3(16, 64, 6), 256, 0, stream>>>(W2,  w2_bf,   4096, 1024, (size_t)4096 * 1024, 0);
  conv_bf16<<<12288, 256, 0, stream>>>(mems, memsbf);
  embed_k<<<8192, 256, 0, stream>>>(data, emb, h, hbf);
  // batched mems-KV GEMM for all 6 layers: kvmem[l] = memsbf[l] @ Wkv[l]
  gemm_bt<128><<<dim3(16, 16, 6), 256, 0, stream>>>(memsbf, wqkv_bf + (size_t)1024 * 1024, nullptr,
      nullptr, kvmem, nullptr, 2048, 2048, 1024, 1024, 0,
      (size_t)2048 * 1024, (size_t)3072 * 1024, (size_t)2048 * 2048);
  // mems-V transpose for all layers (j < 512)
  vtrans<<<dim3(8, 64, 6), 256, 0, stream>>>(kvmem, 2048, 0, vtbf, 0, (size_t)2048 * 2048, VTL);

  for (int l = 0; l < 6; ++l){
    u16* kvm_l = kvmem + (size_t)l * 2048 * 2048;
    u16* vt_l  = vtbf + (size_t)l * VTL;
    // fused Q/KV(h) GEMM: qkv[2048][3072]
    gemm_bt<64><<<dim3(24, 32), 256, 0, stream>>>(hbf, wqkv_bf + (size_t)l * 3072 * 1024, nullptr,
        nullptr, qkv, nullptr, 2048, 3072, 1024, 1024, 0, 0, 0, 0);
    // h-part V transpose (j >= 512)
    vtrans<<<dim3(8, 64), 256, 0, stream>>>(qkv, 3072, 1024, vt_l, 512, 0, 0);
    attn_mfma<<<dim3(8, 64), 256, 0, stream>>>(qkv, kvm_l, vt_l, attnbf);
    // Wo: split-K x2, summed inside ln1
    gemm_bt<64><<<dim3(8, 32, 2), 256, 0, stream>>>(attnbf, wo_bf + (size_t)l * 1024 * 1024, nullptr,
        nullptr, nullptr, pbuf, 2048, 1024, 1024, 512, 0, 0, 0, 0);
    ln_k<<<2048, 256, 0, stream>>>(h, pbuf, PS, 2, nullptr, ln1g + l * 1024, ln1b + l * 1024, h, hbf);
    // W1 + bias + relu
    gemm_bt<64><<<dim3(32, 32), 256, 0, stream>>>(hbf, w1_bf + (size_t)l * 4096 * 1024,
        b1 + (size_t)l * 4096, nullptr, f1bf, nullptr, 2048, 4096, 1024, 1024, 1, 0, 0, 0);
    // W2: split-K x4, summed (+b2) inside ln2
    gemm_bt<64><<<dim3(8, 32, 4), 256, 0, stream>>>(f1bf, w2_bf + (size_t)l * 4096 * 1024, nullptr,
        nullptr, nullptr, pbuf, 2048, 1024, 4096, 1024, 0, 0, 0, 0);
    ln_k<<<2048, 256, 0, stream>>>(h, pbuf, PS, 4, b2 + l * 1024, ln2g + l * 1024, ln2b + l * 1024, h, hbf);
  }
  copy_f32<<<2048, 256, 0, stream>>>((const f32x4*)h, (f32x4*)out);
}